// Round 1
// baseline (1585.848 us; speedup 1.0000x reference)
//
#include <hip/hip_runtime.h>
#include <hip/hip_bf16.h>

// Problem constants (validated against in_sizes at launch)
#define TT 4
#define NN 50000
#define EE 800000
#define FD 128          // F_IN == H == O == 128
#define CC 2

typedef __attribute__((ext_vector_type(8))) short bf16x8;
typedef __attribute__((ext_vector_type(4))) float f32x4;

__device__ __forceinline__ float bf2f(unsigned short h) {
    union { unsigned int u; float f; } v; v.u = ((unsigned int)h) << 16; return v.f;
}
__device__ __forceinline__ unsigned short f2bf(float f) {
    union { float f; unsigned int u; } v; v.f = f;
    unsigned int u = v.u;
    unsigned int r = u + 0x7FFFu + ((u >> 16) & 1u);   // round-to-nearest-even
    return (unsigned short)(r >> 16);
}

// ---------------- CSR build ----------------

__global__ void hist_kernel(const int* __restrict__ dst, int* __restrict__ deg, int e) {
    int i = blockIdx.x * blockDim.x + threadIdx.x;
    if (i < e) atomicAdd(&deg[dst[i]], 1);
}

#define SCAN_BLOCK 1024
__global__ void scan_kernel(const int* __restrict__ deg, int* __restrict__ rowptr, int n) {
    __shared__ int sm[SCAN_BLOCK];
    __shared__ int carry;
    int tid = threadIdx.x;
    if (tid == 0) { carry = 0; rowptr[0] = 0; }
    __syncthreads();
    for (int base = 0; base < n; base += SCAN_BLOCK) {
        int i = base + tid;
        int v = (i < n) ? deg[i] : 0;
        sm[tid] = v;
        __syncthreads();
        #pragma unroll
        for (int off = 1; off < SCAN_BLOCK; off <<= 1) {
            int t = (tid >= off) ? sm[tid - off] : 0;
            __syncthreads();
            sm[tid] += t;
            __syncthreads();
        }
        int c = carry;
        if (i < n) rowptr[i + 1] = sm[tid] + c;
        __syncthreads();                    // all reads of carry done
        if (tid == SCAN_BLOCK - 1) carry = c + sm[tid];
        __syncthreads();                    // update visible before next iter
    }
}

__global__ void fill_kernel(const int* __restrict__ src, const int* __restrict__ dst,
                            int* __restrict__ cursor, int* __restrict__ col, int e) {
    int i = blockIdx.x * blockDim.x + threadIdx.x;
    if (i < e) {
        int p = atomicAdd(&cursor[dst[i]], 1);
        col[p] = src[i];
    }
}

// ---------------- conversions ----------------

__global__ void f32_to_bf16_kernel(const float* __restrict__ in, unsigned short* __restrict__ out, int n4) {
    int i = blockIdx.x * blockDim.x + threadIdx.x;
    if (i < n4) {
        float4 v = *(const float4*)(in + (size_t)i * 4);
        ushort4 o;
        o.x = f2bf(v.x); o.y = f2bf(v.y); o.z = f2bf(v.z); o.w = f2bf(v.w);
        *(ushort4*)(out + (size_t)i * 4) = o;
    }
}

// Wcat[j][k] (k<128 -> Wl[j][k], else Wr[j][k-128]), bf16 [128][256]
__global__ void pack_weights_kernel(const float* __restrict__ Wl, const float* __restrict__ Wr,
                                    unsigned short* __restrict__ out) {
    int i = blockIdx.x * blockDim.x + threadIdx.x;   // 128*256
    if (i < 128 * 256) {
        int j = i >> 8, k = i & 255;
        float v = (k < 128) ? Wl[j * 128 + k] : Wr[j * 128 + (k - 128)];
        out[i] = f2bf(v);
    }
}

// ---------------- gather-mean aggregation (one wave per node) ----------------

__global__ __launch_bounds__(256)
void agg_mean_kernel(const int* __restrict__ rowptr, const int* __restrict__ col,
                     const unsigned short* __restrict__ x, unsigned short* __restrict__ out, int n) {
    int w = (blockIdx.x * blockDim.x + threadIdx.x) >> 6;
    int lane = threadIdx.x & 63;
    if (w >= n) return;
    int beg = rowptr[w];
    int end = rowptr[w + 1];
    float a0 = 0.f, a1 = 0.f;
    int e = beg;
    // 4-way unroll for latency hiding
    for (; e + 4 <= end; e += 4) {
        int s0 = col[e], s1 = col[e + 1], s2 = col[e + 2], s3 = col[e + 3];
        unsigned int v0 = *(const unsigned int*)(x + (size_t)s0 * FD + lane * 2);
        unsigned int v1 = *(const unsigned int*)(x + (size_t)s1 * FD + lane * 2);
        unsigned int v2 = *(const unsigned int*)(x + (size_t)s2 * FD + lane * 2);
        unsigned int v3 = *(const unsigned int*)(x + (size_t)s3 * FD + lane * 2);
        a0 += bf2f((unsigned short)(v0 & 0xFFFF)) + bf2f((unsigned short)(v1 & 0xFFFF))
            + bf2f((unsigned short)(v2 & 0xFFFF)) + bf2f((unsigned short)(v3 & 0xFFFF));
        a1 += bf2f((unsigned short)(v0 >> 16)) + bf2f((unsigned short)(v1 >> 16))
            + bf2f((unsigned short)(v2 >> 16)) + bf2f((unsigned short)(v3 >> 16));
    }
    for (; e < end; ++e) {
        int s = col[e];
        unsigned int v = *(const unsigned int*)(x + (size_t)s * FD + lane * 2);
        a0 += bf2f((unsigned short)(v & 0xFFFF));
        a1 += bf2f((unsigned short)(v >> 16));
    }
    int deg = end - beg;
    float inv = 1.f / (float)(deg > 1 ? deg : 1);
    unsigned int packed = ((unsigned int)f2bf(a1 * inv) << 16) | (unsigned int)f2bf(a0 * inv);
    *(unsigned int*)(out + (size_t)w * FD + lane * 2) = packed;
}

// ---------------- fused SAGE GEMM: out = leaky_relu([Am|Ax] @ Wcat^T + bias) ----------------
// A parts are [N,128] bf16 row-major; Wcat is [128][256] bf16 row-major; K = 256.

__global__ __launch_bounds__(256)
void sage_gemm_kernel(const unsigned short* __restrict__ Am, const unsigned short* __restrict__ Ax,
                      const unsigned short* __restrict__ Wcat, const float* __restrict__ bias,
                      unsigned short* __restrict__ out, int n) {
    int wave = threadIdx.x >> 6;
    int lane = threadIdx.x & 63;
    int m = lane & 15, q = lane >> 4;
    int rowBase = blockIdx.x * 64 + wave * 16;
    int arow = rowBase + m;
    if (arow >= n) arow = n - 1;

    f32x4 acc[8];
    #pragma unroll
    for (int i = 0; i < 8; ++i) acc[i] = (f32x4){0.f, 0.f, 0.f, 0.f};

    #pragma unroll
    for (int step = 0; step < 8; ++step) {
        const unsigned short* Asrc = (step < 4) ? Am : Ax;
        int ka = (step & 3) * 32 + q * 8;                 // k within the 128-wide source
        bf16x8 afrag = *(const bf16x8*)(Asrc + (size_t)arow * FD + ka);
        int kw = step * 32 + q * 8;                       // k within the 256-wide Wcat row
        #pragma unroll
        for (int ct = 0; ct < 8; ++ct) {
            bf16x8 bfrag = *(const bf16x8*)(Wcat + (ct * 16 + m) * 256 + kw);
            acc[ct] = __builtin_amdgcn_mfma_f32_16x16x32_bf16(afrag, bfrag, acc[ct], 0, 0, 0);
        }
    }

    // epilogue: C/D layout col=lane&15, row=q*4+reg
    #pragma unroll
    for (int ct = 0; ct < 8; ++ct) {
        int colc = ct * 16 + m;
        float b = bias[colc];
        #pragma unroll
        for (int r = 0; r < 4; ++r) {
            int row = rowBase + q * 4 + r;
            if (row < n) {
                float v = acc[ct][r] + b;
                v = (v >= 0.f) ? v : 0.2f * v;
                out[(size_t)row * FD + colc] = f2bf(v);
            }
        }
    }
}

// ---------------- classifier: logits[t][i][c] = y2[i] . Wc[c] + bc[c] ----------------

__global__ __launch_bounds__(256)
void classifier_kernel(const unsigned short* __restrict__ y2, const float* __restrict__ Wc,
                       const float* __restrict__ bc, float* __restrict__ logits, int n, int t) {
    int w = (blockIdx.x * blockDim.x + threadIdx.x) >> 6;
    int lane = threadIdx.x & 63;
    if (w >= n) return;
    unsigned int v = *(const unsigned int*)(y2 + (size_t)w * FD + lane * 2);
    float x0 = bf2f((unsigned short)(v & 0xFFFF));
    float x1 = bf2f((unsigned short)(v >> 16));
    float w00 = Wc[lane * 2], w01 = Wc[lane * 2 + 1];
    float w10 = Wc[FD + lane * 2], w11 = Wc[FD + lane * 2 + 1];
    float p0 = x0 * w00 + x1 * w01;
    float p1 = x0 * w10 + x1 * w11;
    #pragma unroll
    for (int off = 32; off > 0; off >>= 1) {
        p0 += __shfl_down(p0, off);
        p1 += __shfl_down(p1, off);
    }
    if (lane == 0) {
        size_t base = ((size_t)t * n + w) * CC;
        logits[base]     = p0 + bc[0];
        logits[base + 1] = p1 + bc[1];
    }
}

// ---------------- log_softmax over node axis ----------------

__global__ void lse_kernel(const float* __restrict__ logits, float* __restrict__ lse, int n) {
    int t = blockIdx.x >> 1, c = blockIdx.x & 1;
    const float* p = logits + (size_t)t * n * CC + c;
    __shared__ float sm[256];
    float m = -1e30f;
    for (int i = threadIdx.x; i < n; i += 256) m = fmaxf(m, p[(size_t)i * CC]);
    sm[threadIdx.x] = m;
    __syncthreads();
    for (int off = 128; off > 0; off >>= 1) {
        if (threadIdx.x < off) sm[threadIdx.x] = fmaxf(sm[threadIdx.x], sm[threadIdx.x + off]);
        __syncthreads();
    }
    m = sm[0];
    __syncthreads();
    float s = 0.f;
    for (int i = threadIdx.x; i < n; i += 256) s += expf(p[(size_t)i * CC] - m);
    sm[threadIdx.x] = s;
    __syncthreads();
    for (int off = 128; off > 0; off >>= 1) {
        if (threadIdx.x < off) sm[threadIdx.x] += sm[threadIdx.x + off];
        __syncthreads();
    }
    if (threadIdx.x == 0) lse[blockIdx.x] = m + logf(sm[0]);
}

__global__ void sub_lse_kernel(const float* __restrict__ logits, const float* __restrict__ lse,
                               float* __restrict__ out, int total, int n) {
    int i = blockIdx.x * blockDim.x + threadIdx.x;
    if (i < total) {
        int c = i & 1;
        int t = i / (n * CC);
        out[i] = logits[i] - lse[t * CC + c];
    }
}

// ---------------- launch ----------------

extern "C" void kernel_launch(void* const* d_in, const int* in_sizes, int n_in,
                              void* d_out, int out_size, void* d_ws, size_t ws_size,
                              hipStream_t stream) {
    const int* graph = (const int*)d_in[0];
    const float* fts = (const float*)d_in[1];
    const float* W1l = (const float*)d_in[3];
    const float* b1  = (const float*)d_in[4];
    const float* W1r = (const float*)d_in[5];
    const float* W2l = (const float*)d_in[6];
    const float* b2  = (const float*)d_in[7];
    const float* W2r = (const float*)d_in[8];
    const float* Wc  = (const float*)d_in[9];
    const float* bc  = (const float*)d_in[10];
    float* out = (float*)d_out;

    const int T = TT;
    const int E = in_sizes[0] / (T * 2);
    const int N = in_sizes[1] / (T * FD);

    // workspace layout
    size_t off = 0;
    auto alloc = [&](size_t bytes) -> char* {
        char* p = (char*)d_ws + off;
        off += (bytes + 511) & ~(size_t)511;
        return p;
    };
    int* rowptr[TT]; int* colidx[TT];
    for (int t = 0; t < T; ++t) rowptr[t] = (int*)alloc((size_t)(N + 1) * 4);
    for (int t = 0; t < T; ++t) colidx[t] = (int*)alloc((size_t)E * 4);
    int* cursor = (int*)alloc((size_t)N * 4);
    unsigned short* xbf     = (unsigned short*)alloc((size_t)N * FD * 2);
    unsigned short* meanbf  = (unsigned short*)alloc((size_t)N * FD * 2);
    unsigned short* ysbf    = (unsigned short*)alloc((size_t)N * FD * 2);
    unsigned short* mean2bf = (unsigned short*)alloc((size_t)N * FD * 2);
    unsigned short* y2bf    = (unsigned short*)alloc((size_t)N * FD * 2);
    unsigned short* wcat1   = (unsigned short*)alloc(128 * 256 * 2);
    unsigned short* wcat2   = (unsigned short*)alloc(128 * 256 * 2);
    float* logits = (float*)alloc((size_t)T * N * CC * 4);
    float* lse    = (float*)alloc(8 * 4);

    // pack weights
    pack_weights_kernel<<<(128 * 256 + 255) / 256, 256, 0, stream>>>(W1l, W1r, wcat1);
    pack_weights_kernel<<<(128 * 256 + 255) / 256, 256, 0, stream>>>(W2l, W2r, wcat2);

    // build CSR per time step
    for (int t = 0; t < T; ++t) {
        const int* src_t = graph + (size_t)t * 2 * E;
        const int* dst_t = src_t + E;
        hipMemsetAsync(cursor, 0, (size_t)N * 4, stream);
        hist_kernel<<<(E + 255) / 256, 256, 0, stream>>>(dst_t, cursor, E);
        scan_kernel<<<1, SCAN_BLOCK, 0, stream>>>(cursor, rowptr[t], N);
        hipMemcpyAsync(cursor, rowptr[t], (size_t)N * 4, hipMemcpyDeviceToDevice, stream);
        fill_kernel<<<(E + 255) / 256, 256, 0, stream>>>(src_t, dst_t, cursor, colidx[t], E);
    }

    const int aggBlocks  = (N * 64 + 255) / 256;
    const int gemmBlocks = (N + 63) / 64;

    for (int t = 0; t < T; ++t) {
        // x_t -> bf16
        f32_to_bf16_kernel<<<((N * FD / 4) + 255) / 256, 256, 0, stream>>>(
            fts + (size_t)t * N * FD, xbf, N * FD / 4);
        // layer 1
        agg_mean_kernel<<<aggBlocks, 256, 0, stream>>>(rowptr[t], colidx[t], xbf, meanbf, N);
        sage_gemm_kernel<<<gemmBlocks, 256, 0, stream>>>(meanbf, xbf, wcat1, b1, ysbf, N);
        // layer 2 (uses last graph)
        agg_mean_kernel<<<aggBlocks, 256, 0, stream>>>(rowptr[T - 1], colidx[T - 1], ysbf, mean2bf, N);
        sage_gemm_kernel<<<gemmBlocks, 256, 0, stream>>>(mean2bf, ysbf, wcat2, b2, y2bf, N);
        // classifier
        classifier_kernel<<<aggBlocks, 256, 0, stream>>>(y2bf, Wc, bc, logits, N, t);
    }

    // log_softmax over node axis
    lse_kernel<<<T * CC, 256, 0, stream>>>(logits, lse, N);
    int total = T * N * CC;
    sub_lse_kernel<<<(total + 255) / 256, 256, 0, stream>>>(logits, lse, out, total, N);
}

// Round 2
// 1170.853 us; speedup vs baseline: 1.3544x; 1.3544x over previous
//
#include <hip/hip_runtime.h>
#include <hip/hip_bf16.h>

#define TT 4
#define FD 128          // F_IN == H == O == 128
#define CC 2
#define LSE_CH 32

typedef __attribute__((ext_vector_type(8))) short bf16x8;
typedef __attribute__((ext_vector_type(4))) float f32x4;

__device__ __forceinline__ float bf2f(unsigned int h) {
    union { unsigned int u; float f; } v; v.u = h << 16; return v.f;
}
__device__ __forceinline__ unsigned short f2bf(float f) {
    union { float f; unsigned int u; } v; v.f = f;
    unsigned int u = v.u;
    unsigned int r = u + 0x7FFFu + ((u >> 16) & 1u);   // round-to-nearest-even
    return (unsigned short)(r >> 16);
}
__device__ __forceinline__ unsigned int pack2(float lo, float hi) {
    return ((unsigned int)f2bf(hi) << 16) | (unsigned int)f2bf(lo);
}
__device__ __forceinline__ void add8(float* a, uint4 v) {
    a[0] += bf2f(v.x & 0xFFFF); a[1] += bf2f(v.x >> 16);
    a[2] += bf2f(v.y & 0xFFFF); a[3] += bf2f(v.y >> 16);
    a[4] += bf2f(v.z & 0xFFFF); a[5] += bf2f(v.z >> 16);
    a[6] += bf2f(v.w & 0xFFFF); a[7] += bf2f(v.w >> 16);
}

// ---------------- CSR build (batched over 4 graphs; blockIdx.y = graph) ----------------
// arr_all[g][i] lifecycle: 0 (memset) -> degree (hist) -> start offset (scan)
//                          -> end offset (fill's atomicAdd). agg uses beg=arr[i-1], end=arr[i].

__global__ void hist_kernel(const int* __restrict__ graph, int* __restrict__ arr, int e, int n) {
    int g = blockIdx.y;
    int i = blockIdx.x * blockDim.x + threadIdx.x;
    const int* dst = graph + (size_t)g * 2 * e + e;
    if (i < e) atomicAdd(&arr[(size_t)g * n + dst[i]], 1);
}

__global__ __launch_bounds__(1024)
void scan_local_kernel(int* __restrict__ arr, int* __restrict__ bsum, int n) {
    int g = blockIdx.y;
    int i = blockIdx.x * 1024 + threadIdx.x;
    int* a = arr + (size_t)g * n;
    __shared__ int sm[1024];
    int v = (i < n) ? a[i] : 0;
    sm[threadIdx.x] = v;
    __syncthreads();
    #pragma unroll
    for (int off = 1; off < 1024; off <<= 1) {
        int t = (threadIdx.x >= off) ? sm[threadIdx.x - off] : 0;
        __syncthreads();
        sm[threadIdx.x] += t;
        __syncthreads();
    }
    if (i < n) a[i] = sm[threadIdx.x] - v;          // exclusive (local)
    if (threadIdx.x == 1023) bsum[g * gridDim.x + blockIdx.x] = sm[1023];
}

// one wave per graph scans its <=64 block sums
__global__ void scan_bsum_kernel(const int* __restrict__ bsum, int* __restrict__ boff, int nb) {
    int g = threadIdx.x >> 6;
    int lane = threadIdx.x & 63;
    int v = (lane < nb) ? bsum[g * nb + lane] : 0;
    int incl = v;
    #pragma unroll
    for (int off = 1; off < 64; off <<= 1) {
        int t = __shfl_up(incl, off, 64);
        if (lane >= off) incl += t;
    }
    if (lane < nb) boff[g * nb + lane] = incl - v;  // exclusive
}

__global__ __launch_bounds__(1024)
void scan_add_kernel(int* __restrict__ arr, const int* __restrict__ boff, int n) {
    int g = blockIdx.y;
    int i = blockIdx.x * 1024 + threadIdx.x;
    if (i < n) arr[(size_t)g * n + i] += boff[g * gridDim.x + blockIdx.x];
}

__global__ void fill_kernel(const int* __restrict__ graph, int* __restrict__ arr,
                            int* __restrict__ col, int e, int n) {
    int g = blockIdx.y;
    int i = blockIdx.x * blockDim.x + threadIdx.x;
    const int* src = graph + (size_t)g * 2 * e;
    const int* dst = src + e;
    if (i < e) {
        int p = atomicAdd(&arr[(size_t)g * n + dst[i]], 1);
        col[(size_t)g * e + p] = src[i];
    }
}

// ---------------- conversions ----------------

__global__ void f32_to_bf16_kernel(const float* __restrict__ in, unsigned short* __restrict__ out, int n4) {
    int i = blockIdx.x * blockDim.x + threadIdx.x;
    if (i < n4) {
        float4 v = *(const float4*)(in + (size_t)i * 4);
        ushort4 o;
        o.x = f2bf(v.x); o.y = f2bf(v.y); o.z = f2bf(v.z); o.w = f2bf(v.w);
        *(ushort4*)(out + (size_t)i * 4) = o;
    }
}

__global__ void pack_weights_kernel(const float* __restrict__ Wl, const float* __restrict__ Wr,
                                    unsigned short* __restrict__ out) {
    int i = blockIdx.x * blockDim.x + threadIdx.x;   // 128*256
    if (i < 128 * 256) {
        int j = i >> 8, k = i & 255;
        float v = (k < 128) ? Wl[j * 128 + k] : Wr[j * 128 + (k - 128)];
        out[i] = f2bf(v);
    }
}

// ---------------- gather-mean: 4 nodes per wave, 16 lanes/node, 16B gathers ----------------

__global__ __launch_bounds__(256)
void agg_mean_kernel(const int* __restrict__ arr, const int* __restrict__ col,
                     const unsigned short* __restrict__ x, unsigned short* __restrict__ out, int n) {
    int t16 = blockIdx.x * 256 + threadIdx.x;
    int node = t16 >> 4;
    int l = threadIdx.x & 15;
    if (node >= n) return;
    int beg = (node == 0) ? 0 : arr[node - 1];
    int end = arr[node];
    float acc[8] = {0.f, 0.f, 0.f, 0.f, 0.f, 0.f, 0.f, 0.f};
    const unsigned short* xb = x + l * 8;
    int e = beg;
    for (; e + 4 <= end; e += 4) {
        int s0 = col[e], s1 = col[e + 1], s2 = col[e + 2], s3 = col[e + 3];
        uint4 v0 = *(const uint4*)(xb + (size_t)s0 * FD);
        uint4 v1 = *(const uint4*)(xb + (size_t)s1 * FD);
        uint4 v2 = *(const uint4*)(xb + (size_t)s2 * FD);
        uint4 v3 = *(const uint4*)(xb + (size_t)s3 * FD);
        add8(acc, v0); add8(acc, v1); add8(acc, v2); add8(acc, v3);
    }
    for (; e < end; ++e) {
        uint4 v = *(const uint4*)(xb + (size_t)col[e] * FD);
        add8(acc, v);
    }
    int deg = end - beg;
    float inv = 1.f / (float)(deg > 1 ? deg : 1);
    uint4 o;
    o.x = pack2(acc[0] * inv, acc[1] * inv);
    o.y = pack2(acc[2] * inv, acc[3] * inv);
    o.z = pack2(acc[4] * inv, acc[5] * inv);
    o.w = pack2(acc[6] * inv, acc[7] * inv);
    *(uint4*)(out + (size_t)node * FD + l * 8) = o;
}

// ---------------- fused SAGE GEMM: out = leaky_relu([Am|Ax] @ Wcat^T + bias) ----------------

__global__ __launch_bounds__(256)
void sage_gemm_kernel(const unsigned short* __restrict__ Am, const unsigned short* __restrict__ Ax,
                      const unsigned short* __restrict__ Wcat, const float* __restrict__ bias,
                      unsigned short* __restrict__ out, int n) {
    int wave = threadIdx.x >> 6;
    int lane = threadIdx.x & 63;
    int m = lane & 15, q = lane >> 4;
    int rowBase = blockIdx.x * 64 + wave * 16;
    int arow = rowBase + m;
    if (arow >= n) arow = n - 1;

    f32x4 acc[8];
    #pragma unroll
    for (int i = 0; i < 8; ++i) acc[i] = (f32x4){0.f, 0.f, 0.f, 0.f};

    #pragma unroll
    for (int step = 0; step < 8; ++step) {
        const unsigned short* Asrc = (step < 4) ? Am : Ax;
        int ka = (step & 3) * 32 + q * 8;
        bf16x8 afrag = *(const bf16x8*)(Asrc + (size_t)arow * FD + ka);
        int kw = step * 32 + q * 8;
        #pragma unroll
        for (int ct = 0; ct < 8; ++ct) {
            bf16x8 bfrag = *(const bf16x8*)(Wcat + (ct * 16 + m) * 256 + kw);
            acc[ct] = __builtin_amdgcn_mfma_f32_16x16x32_bf16(afrag, bfrag, acc[ct], 0, 0, 0);
        }
    }

    #pragma unroll
    for (int ct = 0; ct < 8; ++ct) {
        int colc = ct * 16 + m;
        float b = bias[colc];
        #pragma unroll
        for (int r = 0; r < 4; ++r) {
            int row = rowBase + q * 4 + r;
            if (row < n) {
                float v = acc[ct][r] + b;
                v = (v >= 0.f) ? v : 0.2f * v;
                out[(size_t)row * FD + colc] = f2bf(v);
            }
        }
    }
}

// ---------------- classifier ----------------

__global__ __launch_bounds__(256)
void classifier_kernel(const unsigned short* __restrict__ y2, const float* __restrict__ Wc,
                       const float* __restrict__ bc, float* __restrict__ logits, int n, int t) {
    int w = (blockIdx.x * blockDim.x + threadIdx.x) >> 6;
    int lane = threadIdx.x & 63;
    if (w >= n) return;
    unsigned int v = *(const unsigned int*)(y2 + (size_t)w * FD + lane * 2);
    float x0 = bf2f(v & 0xFFFF);
    float x1 = bf2f(v >> 16);
    float p0 = x0 * Wc[lane * 2] + x1 * Wc[lane * 2 + 1];
    float p1 = x0 * Wc[FD + lane * 2] + x1 * Wc[FD + lane * 2 + 1];
    #pragma unroll
    for (int off = 32; off > 0; off >>= 1) {
        p0 += __shfl_down(p0, off);
        p1 += __shfl_down(p1, off);
    }
    if (lane == 0) {
        size_t base = ((size_t)t * n + w) * CC;
        logits[base]     = p0 + bc[0];
        logits[base + 1] = p1 + bc[1];
    }
}

// ---------------- log_softmax over node axis (2-stage online) ----------------

__global__ __launch_bounds__(256)
void lse_partial_kernel(const float* __restrict__ logits, float* __restrict__ pm,
                        float* __restrict__ ps, int n) {
    int tc = blockIdx.y;
    int t = tc >> 1, c = tc & 1;
    const float* p = logits + (size_t)t * n * CC + c;
    float m = -1e30f, s = 0.f;
    for (int i = blockIdx.x * 256 + threadIdx.x; i < n; i += LSE_CH * 256) {
        float v = p[(size_t)i * CC];
        if (v > m) { s = s * __expf(m - v) + 1.f; m = v; }
        else s += __expf(v - m);
    }
    __shared__ float smm[256], sms[256];
    smm[threadIdx.x] = m; sms[threadIdx.x] = s;
    __syncthreads();
    for (int off = 128; off > 0; off >>= 1) {
        if (threadIdx.x < off) {
            float m2 = smm[threadIdx.x + off], s2 = sms[threadIdx.x + off];
            float M = fmaxf(smm[threadIdx.x], m2);
            sms[threadIdx.x] = sms[threadIdx.x] * __expf(smm[threadIdx.x] - M) + s2 * __expf(m2 - M);
            smm[threadIdx.x] = M;
        }
        __syncthreads();
    }
    if (threadIdx.x == 0) { pm[tc * LSE_CH + blockIdx.x] = smm[0]; ps[tc * LSE_CH + blockIdx.x] = sms[0]; }
}

__global__ void lse_final_kernel(const float* __restrict__ pm, const float* __restrict__ ps,
                                 float* __restrict__ lse) {
    int tc = blockIdx.x;
    int lane = threadIdx.x;
    float m = (lane < LSE_CH) ? pm[tc * LSE_CH + lane] : -1e30f;
    float s = (lane < LSE_CH) ? ps[tc * LSE_CH + lane] : 0.f;
    #pragma unroll
    for (int off = 32; off > 0; off >>= 1) {
        float m2 = __shfl_down(m, off);
        float s2 = __shfl_down(s, off);
        float M = fmaxf(m, m2);
        s = s * __expf(m - M) + s2 * __expf(m2 - M);
        m = M;
    }
    if (lane == 0) lse[tc] = m + logf(s);
}

__global__ void sub_lse_kernel(const float* __restrict__ logits, const float* __restrict__ lse,
                               float* __restrict__ out, int total, int n) {
    int i = blockIdx.x * blockDim.x + threadIdx.x;
    if (i < total) {
        int c = i & 1;
        int t = i / (n * CC);
        out[i] = logits[i] - lse[t * CC + c];
    }
}

// ---------------- launch ----------------

extern "C" void kernel_launch(void* const* d_in, const int* in_sizes, int n_in,
                              void* d_out, int out_size, void* d_ws, size_t ws_size,
                              hipStream_t stream) {
    const int* graph = (const int*)d_in[0];
    const float* fts = (const float*)d_in[1];
    const float* W1l = (const float*)d_in[3];
    const float* b1  = (const float*)d_in[4];
    const float* W1r = (const float*)d_in[5];
    const float* W2l = (const float*)d_in[6];
    const float* b2  = (const float*)d_in[7];
    const float* W2r = (const float*)d_in[8];
    const float* Wc  = (const float*)d_in[9];
    const float* bc  = (const float*)d_in[10];
    float* out = (float*)d_out;

    const int T = TT;
    const int E = in_sizes[0] / (T * 2);
    const int N = in_sizes[1] / (T * FD);
    const int NB = (N + 1023) / 1024;            // blocks/graph for scan (must be <= 64)

    size_t off = 0;
    auto alloc = [&](size_t bytes) -> char* {
        char* p = (char*)d_ws + off;
        off += (bytes + 511) & ~(size_t)511;
        return p;
    };
    int* arr_all = (int*)alloc((size_t)T * N * 4);          // deg -> start -> end offsets
    int* col_all = (int*)alloc((size_t)T * E * 4);
    int* bsum    = (int*)alloc((size_t)T * NB * 4);
    int* boff    = (int*)alloc((size_t)T * NB * 4);
    unsigned short* bufA = (unsigned short*)alloc((size_t)N * FD * 2);   // x_t / y2
    unsigned short* bufB = (unsigned short*)alloc((size_t)N * FD * 2);   // mean1 / mean2
    unsigned short* bufC = (unsigned short*)alloc((size_t)N * FD * 2);   // ys
    unsigned short* wcat1 = (unsigned short*)alloc(128 * 256 * 2);
    unsigned short* wcat2 = (unsigned short*)alloc(128 * 256 * 2);
    float* logits = (float*)alloc((size_t)T * N * CC * 4);
    float* pm  = (float*)alloc((size_t)T * CC * LSE_CH * 4);
    float* ps  = (float*)alloc((size_t)T * CC * LSE_CH * 4);
    float* lse = (float*)alloc(T * CC * 4);

    pack_weights_kernel<<<(128 * 256 + 255) / 256, 256, 0, stream>>>(W1l, W1r, wcat1);
    pack_weights_kernel<<<(128 * 256 + 255) / 256, 256, 0, stream>>>(W2l, W2r, wcat2);

    // CSR build, all graphs at once
    hipMemsetAsync(arr_all, 0, (size_t)T * N * 4, stream);
    dim3 egrid((E + 255) / 256, T);
    hist_kernel<<<egrid, 256, 0, stream>>>(graph, arr_all, E, N);
    dim3 sgrid(NB, T);
    scan_local_kernel<<<sgrid, 1024, 0, stream>>>(arr_all, bsum, N);
    scan_bsum_kernel<<<1, 256, 0, stream>>>(bsum, boff, NB);
    scan_add_kernel<<<sgrid, 1024, 0, stream>>>(arr_all, boff, N);
    fill_kernel<<<egrid, 256, 0, stream>>>(graph, arr_all, col_all, E, N);
    // arr_all[g][i] now holds END offset of node i; beg = arr_all[g][i-1] (0 for i==0)

    const int aggBlocks  = (N * 16 + 255) / 256;
    const int wavBlocks  = (N * 64 + 255) / 256;
    const int gemmBlocks = (N + 63) / 64;
    const int* arrL = arr_all + (size_t)(T - 1) * N;     // last graph
    const int* colL = col_all + (size_t)(T - 1) * E;

    for (int t = 0; t < T; ++t) {
        f32_to_bf16_kernel<<<((N * FD / 4) + 255) / 256, 256, 0, stream>>>(
            fts + (size_t)t * N * FD, bufA, N * FD / 4);
        agg_mean_kernel<<<aggBlocks, 256, 0, stream>>>(arr_all + (size_t)t * N,
                                                       col_all + (size_t)t * E, bufA, bufB, N);
        sage_gemm_kernel<<<gemmBlocks, 256, 0, stream>>>(bufB, bufA, wcat1, b1, bufC, N);
        agg_mean_kernel<<<aggBlocks, 256, 0, stream>>>(arrL, colL, bufC, bufB, N);
        sage_gemm_kernel<<<gemmBlocks, 256, 0, stream>>>(bufB, bufC, wcat2, b2, bufA, N);
        classifier_kernel<<<wavBlocks, 256, 0, stream>>>(bufA, Wc, bc, logits, N, t);
    }

    dim3 lgrid(LSE_CH, T * CC);
    lse_partial_kernel<<<lgrid, 256, 0, stream>>>(logits, pm, ps, N);
    lse_final_kernel<<<T * CC, 64, 0, stream>>>(pm, ps, lse);
    int total = T * N * CC;
    sub_lse_kernel<<<(total + 255) / 256, 256, 0, stream>>>(logits, lse, out, total, N);
}

// Round 3
// 1054.692 us; speedup vs baseline: 1.5036x; 1.1101x over previous
//
#include <hip/hip_runtime.h>
#include <hip/hip_bf16.h>

#define TT 4
#define FD 128          // F_IN == H == O == 128
#define CC 2
#define LSE_CH 32

typedef __attribute__((ext_vector_type(8))) short bf16x8;
typedef __attribute__((ext_vector_type(4))) float f32x4;

__device__ __forceinline__ float bf2f(unsigned int h) {
    union { unsigned int u; float f; } v; v.u = h << 16; return v.f;
}
__device__ __forceinline__ unsigned short f2bf(float f) {
    union { float f; unsigned int u; } v; v.f = f;
    unsigned int u = v.u;
    unsigned int r = u + 0x7FFFu + ((u >> 16) & 1u);   // round-to-nearest-even
    return (unsigned short)(r >> 16);
}
__device__ __forceinline__ unsigned int pack2(float lo, float hi) {
    return ((unsigned int)f2bf(hi) << 16) | (unsigned int)f2bf(lo);
}
__device__ __forceinline__ void add8(float* a, uint4 v) {
    a[0] += bf2f(v.x & 0xFFFF); a[1] += bf2f(v.x >> 16);
    a[2] += bf2f(v.y & 0xFFFF); a[3] += bf2f(v.y >> 16);
    a[4] += bf2f(v.z & 0xFFFF); a[5] += bf2f(v.z >> 16);
    a[6] += bf2f(v.w & 0xFFFF); a[7] += bf2f(v.w >> 16);
}

// ---------------- CSR build (batched over 4 graphs; blockIdx.y = graph) ----------------
// arr_all[g][i]: 0 -> degree -> start offset -> end offset (after fill).

__global__ void hist_kernel(const int* __restrict__ graph, int* __restrict__ arr, int e, int n) {
    int g = blockIdx.y;
    int i = blockIdx.x * blockDim.x + threadIdx.x;
    const int* dst = graph + (size_t)g * 2 * e + e;
    if (i < e) atomicAdd(&arr[(size_t)g * n + dst[i]], 1);
}

__global__ __launch_bounds__(1024)
void scan_local_kernel(int* __restrict__ arr, int* __restrict__ bsum, int n) {
    int g = blockIdx.y;
    int i = blockIdx.x * 1024 + threadIdx.x;
    int* a = arr + (size_t)g * n;
    __shared__ int sm[1024];
    int v = (i < n) ? a[i] : 0;
    sm[threadIdx.x] = v;
    __syncthreads();
    #pragma unroll
    for (int off = 1; off < 1024; off <<= 1) {
        int t = (threadIdx.x >= off) ? sm[threadIdx.x - off] : 0;
        __syncthreads();
        sm[threadIdx.x] += t;
        __syncthreads();
    }
    if (i < n) a[i] = sm[threadIdx.x] - v;          // exclusive (local)
    if (threadIdx.x == 1023) bsum[g * gridDim.x + blockIdx.x] = sm[1023];
}

__global__ void scan_bsum_kernel(const int* __restrict__ bsum, int* __restrict__ boff, int nb) {
    int g = threadIdx.x >> 6;
    int lane = threadIdx.x & 63;
    int v = (lane < nb) ? bsum[g * nb + lane] : 0;
    int incl = v;
    #pragma unroll
    for (int off = 1; off < 64; off <<= 1) {
        int t = __shfl_up(incl, off, 64);
        if (lane >= off) incl += t;
    }
    if (lane < nb) boff[g * nb + lane] = incl - v;  // exclusive
}

__global__ __launch_bounds__(1024)
void scan_add_kernel(int* __restrict__ arr, const int* __restrict__ boff, int n) {
    int g = blockIdx.y;
    int i = blockIdx.x * 1024 + threadIdx.x;
    if (i < n) arr[(size_t)g * n + i] += boff[g * gridDim.x + blockIdx.x];
}

__global__ void fill_kernel(const int* __restrict__ graph, int* __restrict__ arr,
                            unsigned short* __restrict__ col, int e, int n) {
    int g = blockIdx.y;
    int i = blockIdx.x * blockDim.x + threadIdx.x;
    const int* src = graph + (size_t)g * 2 * e;
    const int* dst = src + e;
    if (i < e) {
        int p = atomicAdd(&arr[(size_t)g * n + dst[i]], 1);
        col[(size_t)g * e + p] = (unsigned short)src[i];
    }
}

// ---------------- conversions ----------------

__global__ void f32_to_bf16_kernel(const float* __restrict__ in, unsigned short* __restrict__ out, int n4) {
    int i = blockIdx.x * blockDim.x + threadIdx.x;
    if (i < n4) {
        float4 v = *(const float4*)(in + (size_t)i * 4);
        ushort4 o;
        o.x = f2bf(v.x); o.y = f2bf(v.y); o.z = f2bf(v.z); o.w = f2bf(v.w);
        *(ushort4*)(out + (size_t)i * 4) = o;
    }
}

__global__ void pack_weights_kernel(const float* __restrict__ Wl, const float* __restrict__ Wr,
                                    unsigned short* __restrict__ out) {
    int i = blockIdx.x * blockDim.x + threadIdx.x;   // 128*256
    if (i < 128 * 256) {
        int j = i >> 8, k = i & 255;
        float v = (k < 128) ? Wl[j * 128 + k] : Wr[j * 128 + (k - 128)];
        out[i] = f2bf(v);
    }
}

// ---------------- layer-1 gather-mean: 4 nodes/wave, 16 lanes/node, 8-deep unroll ----------------

__global__ __launch_bounds__(256)
void agg1_kernel(const int* __restrict__ arr, const unsigned short* __restrict__ col,
                 const unsigned short* __restrict__ x, unsigned short* __restrict__ out, int n) {
    int node = (blockIdx.x * 256 + threadIdx.x) >> 4;
    int l = threadIdx.x & 15;
    if (node >= n) return;
    int beg = (node == 0) ? 0 : arr[node - 1];
    int end = arr[node];
    float acc[8] = {0.f, 0.f, 0.f, 0.f, 0.f, 0.f, 0.f, 0.f};
    const unsigned short* xb = x + l * 8;
    int e = beg;
    for (; e + 8 <= end; e += 8) {
        uint4 v[8];
        #pragma unroll
        for (int j = 0; j < 8; ++j)
            v[j] = *(const uint4*)(xb + (size_t)col[e + j] * FD);
        #pragma unroll
        for (int j = 0; j < 8; ++j) add8(acc, v[j]);
    }
    for (; e < end; ++e)
        add8(acc, *(const uint4*)(xb + (size_t)col[e] * FD));
    int deg = end - beg;
    float inv = 1.f / (float)(deg > 1 ? deg : 1);
    uint4 o;
    o.x = pack2(acc[0] * inv, acc[1] * inv);
    o.y = pack2(acc[2] * inv, acc[3] * inv);
    o.z = pack2(acc[4] * inv, acc[5] * inv);
    o.w = pack2(acc[6] * inv, acc[7] * inv);
    *(uint4*)(out + (size_t)node * FD + l * 8) = o;
}

// ---------------- layer-2 gather-mean, fused over 4 time steps: 1 wave/node ----------------
// lane = t*16 + l ; gathers from ys[t][col[e]][l*8..] ; writes mean2[t][node][l*8..]

__global__ __launch_bounds__(256)
void agg2_kernel(const int* __restrict__ arr, const unsigned short* __restrict__ col,
                 const unsigned short* __restrict__ ys, unsigned short* __restrict__ out, int n) {
    int node = (blockIdx.x * 256 + threadIdx.x) >> 6;
    int lane = threadIdx.x & 63;
    if (node >= n) return;
    int t = lane >> 4, l = lane & 15;
    int beg = (node == 0) ? 0 : arr[node - 1];
    int end = arr[node];
    float acc[8] = {0.f, 0.f, 0.f, 0.f, 0.f, 0.f, 0.f, 0.f};
    const unsigned short* xb = ys + (size_t)t * n * FD + l * 8;
    int e = beg;
    for (; e + 8 <= end; e += 8) {
        uint4 v[8];
        #pragma unroll
        for (int j = 0; j < 8; ++j)
            v[j] = *(const uint4*)(xb + (size_t)col[e + j] * FD);
        #pragma unroll
        for (int j = 0; j < 8; ++j) add8(acc, v[j]);
    }
    for (; e < end; ++e)
        add8(acc, *(const uint4*)(xb + (size_t)col[e] * FD));
    int deg = end - beg;
    float inv = 1.f / (float)(deg > 1 ? deg : 1);
    uint4 o;
    o.x = pack2(acc[0] * inv, acc[1] * inv);
    o.y = pack2(acc[2] * inv, acc[3] * inv);
    o.z = pack2(acc[4] * inv, acc[5] * inv);
    o.w = pack2(acc[6] * inv, acc[7] * inv);
    *(uint4*)(out + ((size_t)t * n + node) * FD + l * 8) = o;
}

// ---------------- SAGE GEMM layer 1: ys = leaky_relu([Am|Ax] @ Wcat^T + bias) ----------------

__global__ __launch_bounds__(256)
void sage_gemm_kernel(const unsigned short* __restrict__ Am, const unsigned short* __restrict__ Ax,
                      const unsigned short* __restrict__ Wcat, const float* __restrict__ bias,
                      unsigned short* __restrict__ out, int n) {
    int wave = threadIdx.x >> 6;
    int lane = threadIdx.x & 63;
    int m = lane & 15, q = lane >> 4;
    int rowBase = blockIdx.x * 64 + wave * 16;
    int arow = rowBase + m;
    if (arow >= n) arow = n - 1;

    f32x4 acc[8];
    #pragma unroll
    for (int i = 0; i < 8; ++i) acc[i] = (f32x4){0.f, 0.f, 0.f, 0.f};

    #pragma unroll
    for (int step = 0; step < 8; ++step) {
        const unsigned short* Asrc = (step < 4) ? Am : Ax;
        int ka = (step & 3) * 32 + q * 8;
        bf16x8 afrag = *(const bf16x8*)(Asrc + (size_t)arow * FD + ka);
        int kw = step * 32 + q * 8;
        #pragma unroll
        for (int ct = 0; ct < 8; ++ct) {
            bf16x8 bfrag = *(const bf16x8*)(Wcat + (ct * 16 + m) * 256 + kw);
            acc[ct] = __builtin_amdgcn_mfma_f32_16x16x32_bf16(afrag, bfrag, acc[ct], 0, 0, 0);
        }
    }

    #pragma unroll
    for (int ct = 0; ct < 8; ++ct) {
        int colc = ct * 16 + m;
        float b = bias[colc];
        #pragma unroll
        for (int r = 0; r < 4; ++r) {
            int row = rowBase + q * 4 + r;
            if (row < n) {
                float v = acc[ct][r] + b;
                v = (v >= 0.f) ? v : 0.2f * v;
                out[(size_t)row * FD + colc] = f2bf(v);
            }
        }
    }
}

// ---------------- SAGE GEMM layer 2 fused with classifier: logits = leaky(...) @ Wc^T + bc ----

__global__ __launch_bounds__(256)
void gemm2_cls_kernel(const unsigned short* __restrict__ Am, const unsigned short* __restrict__ Ax,
                      const unsigned short* __restrict__ Wcat, const float* __restrict__ bias,
                      const float* __restrict__ Wc, const float* __restrict__ bc,
                      float* __restrict__ logits, int mrows) {
    int wave = threadIdx.x >> 6;
    int lane = threadIdx.x & 63;
    int m = lane & 15, q = lane >> 4;
    int rowBase = blockIdx.x * 64 + wave * 16;
    int arow = rowBase + m;
    if (arow >= mrows) arow = mrows - 1;

    f32x4 acc[8];
    #pragma unroll
    for (int i = 0; i < 8; ++i) acc[i] = (f32x4){0.f, 0.f, 0.f, 0.f};

    #pragma unroll
    for (int step = 0; step < 8; ++step) {
        const unsigned short* Asrc = (step < 4) ? Am : Ax;
        int ka = (step & 3) * 32 + q * 8;
        bf16x8 afrag = *(const bf16x8*)(Asrc + (size_t)arow * FD + ka);
        int kw = step * 32 + q * 8;
        #pragma unroll
        for (int ct = 0; ct < 8; ++ct) {
            bf16x8 bfrag = *(const bf16x8*)(Wcat + (ct * 16 + m) * 256 + kw);
            acc[ct] = __builtin_amdgcn_mfma_f32_16x16x32_bf16(afrag, bfrag, acc[ct], 0, 0, 0);
        }
    }

    // classifier weights for this lane's 8 columns
    float wc0[8], wc1[8], bb[8];
    #pragma unroll
    for (int ct = 0; ct < 8; ++ct) {
        wc0[ct] = Wc[ct * 16 + m];
        wc1[ct] = Wc[FD + ct * 16 + m];
        bb[ct]  = bias[ct * 16 + m];
    }
    float bc0 = bc[0], bc1 = bc[1];

    #pragma unroll
    for (int r = 0; r < 4; ++r) {
        float p0 = 0.f, p1 = 0.f;
        #pragma unroll
        for (int ct = 0; ct < 8; ++ct) {
            float v = acc[ct][r] + bb[ct];
            v = (v >= 0.f) ? v : 0.2f * v;
            p0 += v * wc0[ct];
            p1 += v * wc1[ct];
        }
        #pragma unroll
        for (int off = 8; off > 0; off >>= 1) {
            p0 += __shfl_down(p0, off);
            p1 += __shfl_down(p1, off);
        }
        if (m == 0) {
            int row = rowBase + q * 4 + r;
            if (row < mrows) {
                logits[(size_t)row * CC]     = p0 + bc0;
                logits[(size_t)row * CC + 1] = p1 + bc1;
            }
        }
    }
}

// ---------------- log_softmax over node axis (2-stage online) ----------------

__global__ __launch_bounds__(256)
void lse_partial_kernel(const float* __restrict__ logits, float* __restrict__ pm,
                        float* __restrict__ ps, int n) {
    int tc = blockIdx.y;
    int t = tc >> 1, c = tc & 1;
    const float* p = logits + (size_t)t * n * CC + c;
    float m = -1e30f, s = 0.f;
    for (int i = blockIdx.x * 256 + threadIdx.x; i < n; i += LSE_CH * 256) {
        float v = p[(size_t)i * CC];
        if (v > m) { s = s * __expf(m - v) + 1.f; m = v; }
        else s += __expf(v - m);
    }
    __shared__ float smm[256], sms[256];
    smm[threadIdx.x] = m; sms[threadIdx.x] = s;
    __syncthreads();
    for (int off = 128; off > 0; off >>= 1) {
        if (threadIdx.x < off) {
            float m2 = smm[threadIdx.x + off], s2 = sms[threadIdx.x + off];
            float M = fmaxf(smm[threadIdx.x], m2);
            sms[threadIdx.x] = sms[threadIdx.x] * __expf(smm[threadIdx.x] - M) + s2 * __expf(m2 - M);
            smm[threadIdx.x] = M;
        }
        __syncthreads();
    }
    if (threadIdx.x == 0) { pm[tc * LSE_CH + blockIdx.x] = smm[0]; ps[tc * LSE_CH + blockIdx.x] = sms[0]; }
}

__global__ void lse_final_kernel(const float* __restrict__ pm, const float* __restrict__ ps,
                                 float* __restrict__ lse) {
    int tc = blockIdx.x;
    int lane = threadIdx.x;
    float m = (lane < LSE_CH) ? pm[tc * LSE_CH + lane] : -1e30f;
    float s = (lane < LSE_CH) ? ps[tc * LSE_CH + lane] : 0.f;
    #pragma unroll
    for (int off = 32; off > 0; off >>= 1) {
        float m2 = __shfl_down(m, off);
        float s2 = __shfl_down(s, off);
        float M = fmaxf(m, m2);
        s = s * __expf(m - M) + s2 * __expf(m2 - M);
        m = M;
    }
    if (lane == 0) lse[tc] = m + logf(s);
}

__global__ void sub_lse_kernel(const float* __restrict__ logits, const float* __restrict__ lse,
                               float* __restrict__ out, int total, int n) {
    int i = blockIdx.x * blockDim.x + threadIdx.x;
    if (i < total) {
        int c = i & 1;
        int t = i / (n * CC);
        out[i] = logits[i] - lse[t * CC + c];
    }
}

// ---------------- launch ----------------

extern "C" void kernel_launch(void* const* d_in, const int* in_sizes, int n_in,
                              void* d_out, int out_size, void* d_ws, size_t ws_size,
                              hipStream_t stream) {
    const int* graph = (const int*)d_in[0];
    const float* fts = (const float*)d_in[1];
    const float* W1l = (const float*)d_in[3];
    const float* b1  = (const float*)d_in[4];
    const float* W1r = (const float*)d_in[5];
    const float* W2l = (const float*)d_in[6];
    const float* b2  = (const float*)d_in[7];
    const float* W2r = (const float*)d_in[8];
    const float* Wc  = (const float*)d_in[9];
    const float* bc  = (const float*)d_in[10];
    float* out = (float*)d_out;

    const int T = TT;
    const int E = in_sizes[0] / (T * 2);
    const int N = in_sizes[1] / (T * FD);
    const int NB = (N + 1023) / 1024;            // <= 64

    size_t off = 0;
    auto alloc = [&](size_t bytes) -> char* {
        char* p = (char*)d_ws + off;
        off += (bytes + 511) & ~(size_t)511;
        return p;
    };
    int* arr_all = (int*)alloc((size_t)T * N * 4);
    unsigned short* col_all = (unsigned short*)alloc((size_t)T * E * 2);
    int* bsum = (int*)alloc((size_t)T * NB * 4);
    int* boff = (int*)alloc((size_t)T * NB * 4);
    unsigned short* ysall = (unsigned short*)alloc((size_t)T * N * FD * 2);
    unsigned short* wcat1 = (unsigned short*)alloc(128 * 256 * 2);
    unsigned short* wcat2 = (unsigned short*)alloc(128 * 256 * 2);
    float* logits = (float*)alloc((size_t)T * N * CC * 4);
    float* pm  = (float*)alloc((size_t)T * CC * LSE_CH * 4);
    float* ps  = (float*)alloc((size_t)T * CC * LSE_CH * 4);
    float* lse = (float*)alloc(T * CC * 4);
    // aliased scratch: {xbf, mean1} during layer 1; mean2all (4x N*FD) afterwards
    unsigned short* scratch = (unsigned short*)alloc((size_t)T * N * FD * 2);
    unsigned short* xbf   = scratch;
    unsigned short* mean1 = scratch + (size_t)N * FD;
    unsigned short* mean2all = scratch;

    pack_weights_kernel<<<(128 * 256 + 255) / 256, 256, 0, stream>>>(W1l, W1r, wcat1);
    pack_weights_kernel<<<(128 * 256 + 255) / 256, 256, 0, stream>>>(W2l, W2r, wcat2);

    // CSR build, all graphs
    hipMemsetAsync(arr_all, 0, (size_t)T * N * 4, stream);
    dim3 egrid((E + 255) / 256, T);
    hist_kernel<<<egrid, 256, 0, stream>>>(graph, arr_all, E, N);
    dim3 sgrid(NB, T);
    scan_local_kernel<<<sgrid, 1024, 0, stream>>>(arr_all, bsum, N);
    scan_bsum_kernel<<<1, 256, 0, stream>>>(bsum, boff, NB);
    scan_add_kernel<<<sgrid, 1024, 0, stream>>>(arr_all, boff, N);
    fill_kernel<<<egrid, 256, 0, stream>>>(graph, arr_all, col_all, E, N);

    const int aggBlocks  = (N * 16 + 255) / 256;
    const int wavBlocks  = (N * 64 + 255) / 256;
    const int gemmBlocks = (N + 63) / 64;
    const int* arrL = arr_all + (size_t)(T - 1) * N;
    const unsigned short* colL = col_all + (size_t)(T - 1) * E;

    // layer 1 per time step
    for (int t = 0; t < T; ++t) {
        f32_to_bf16_kernel<<<((N * FD / 4) + 255) / 256, 256, 0, stream>>>(
            fts + (size_t)t * N * FD, xbf, N * FD / 4);
        agg1_kernel<<<aggBlocks, 256, 0, stream>>>(arr_all + (size_t)t * N,
                                                   col_all + (size_t)t * E, xbf, mean1, N);
        sage_gemm_kernel<<<gemmBlocks, 256, 0, stream>>>(mean1, xbf, wcat1, b1,
                                                         ysall + (size_t)t * N * FD, N);
    }

    // layer 2: fused aggregation over 4 t's (last graph), then fused GEMM+classifier
    agg2_kernel<<<wavBlocks, 256, 0, stream>>>(arrL, colL, ysall, mean2all, N);
    int mrows = T * N;
    gemm2_cls_kernel<<<(mrows + 63) / 64, 256, 0, stream>>>(mean2all, ysall, wcat2, b2,
                                                            Wc, bc, logits, mrows);

    dim3 lgrid(LSE_CH, T * CC);
    lse_partial_kernel<<<lgrid, 256, 0, stream>>>(logits, pm, ps, N);
    lse_final_kernel<<<T * CC, 64, 0, stream>>>(pm, ps, lse);
    int total = T * N * CC;
    sub_lse_kernel<<<(total + 255) / 256, 256, 0, stream>>>(logits, lse, out, total, N);
}

// Round 4
// 791.651 us; speedup vs baseline: 2.0032x; 1.3323x over previous
//
#include <hip/hip_runtime.h>
#include <hip/hip_bf16.h>

#define TT 4
#define FD 128          // F_IN == H == O == 128
#define CC 2
#define LSE_CH 32

// binning parameters
#define NPB 64          // nodes per bucket
#define NPB_SHIFT 6
#define NBUKMAX 1024    // ceil(50000/64) = 782 <= 1024
#define CAP 1536        // per-bucket record capacity (mean 1023, +16 sigma)
#define BIN_TILE 8192

typedef __attribute__((ext_vector_type(8))) short bf16x8;
typedef __attribute__((ext_vector_type(4))) float f32x4;

__device__ __forceinline__ float bf2f(unsigned int h) {
    union { unsigned int u; float f; } v; v.u = h << 16; return v.f;
}
__device__ __forceinline__ unsigned short f2bf(float f) {
    union { float f; unsigned int u; } v; v.f = f;
    unsigned int u = v.u;
    unsigned int r = u + 0x7FFFu + ((u >> 16) & 1u);   // round-to-nearest-even
    return (unsigned short)(r >> 16);
}
__device__ __forceinline__ unsigned int pack2(float lo, float hi) {
    return ((unsigned int)f2bf(hi) << 16) | (unsigned int)f2bf(lo);
}
__device__ __forceinline__ void add8(float* a, uint4 v) {
    a[0] += bf2f(v.x & 0xFFFF); a[1] += bf2f(v.x >> 16);
    a[2] += bf2f(v.y & 0xFFFF); a[3] += bf2f(v.y >> 16);
    a[4] += bf2f(v.z & 0xFFFF); a[5] += bf2f(v.z >> 16);
    a[6] += bf2f(v.w & 0xFFFF); a[7] += bf2f(v.w >> 16);
}

// ---------------- CSR build via two-level binning (replaces hist/scan/fill) ----------------
// Pass 1: bin edges into 782 dst-buckets (64 nodes each), records packed (dstLocal<<16 | src).
// Writes per (tile,bucket) are contiguous -> near-line-granular efficiency.

__global__ __launch_bounds__(256)
void bin_kernel(const int* __restrict__ graph, int* __restrict__ gcount,
                unsigned int* __restrict__ bdata, int e, int nbuk) {
    int g = blockIdx.y;
    const int* src = graph + (size_t)g * 2 * e;
    const int* dst = src + e;
    int tbeg = blockIdx.x * BIN_TILE;
    int tend = tbeg + BIN_TILE < e ? tbeg + BIN_TILE : e;
    __shared__ int cnt[NBUKMAX];
    __shared__ int base[NBUKMAX];
    for (int i = threadIdx.x; i < nbuk; i += 256) cnt[i] = 0;
    __syncthreads();
    for (int i = tbeg + threadIdx.x; i < tend; i += 256)
        atomicAdd(&cnt[dst[i] >> NPB_SHIFT], 1);
    __syncthreads();
    for (int i = threadIdx.x; i < nbuk; i += 256) {
        int c = cnt[i];
        base[i] = (c > 0) ? atomicAdd(&gcount[g * nbuk + i], c) : 0;
        cnt[i] = 0;                         // reuse as cursor
    }
    __syncthreads();
    for (int i = tbeg + threadIdx.x; i < tend; i += 256) {
        int d = dst[i];
        int b = d >> NPB_SHIFT;
        int pos = base[b] + atomicAdd(&cnt[b], 1);
        if (pos < CAP)
            bdata[((size_t)g * nbuk + b) * CAP + pos] =
                ((unsigned int)(d & (NPB - 1)) << 16) | (unsigned int)src[i];
    }
}

// Pass 2a: exclusive scan of bucket counts (one block per graph, nbuk <= 1024)
__global__ __launch_bounds__(1024)
void bucket_scan_kernel(const int* __restrict__ gcount, int* __restrict__ bbase, int nbuk) {
    int g = blockIdx.x;
    __shared__ int sm[1024];
    int v = (threadIdx.x < nbuk) ? gcount[g * nbuk + threadIdx.x] : 0;
    sm[threadIdx.x] = v;
    __syncthreads();
    #pragma unroll
    for (int off = 1; off < 1024; off <<= 1) {
        int t = (threadIdx.x >= off) ? sm[threadIdx.x - off] : 0;
        __syncthreads();
        sm[threadIdx.x] += t;
        __syncthreads();
    }
    if (threadIdx.x < nbuk) bbase[g * nbuk + threadIdx.x] = sm[threadIdx.x] - v;
}

// Pass 2b: one block per bucket — node degrees in LDS, 64-lane scan, write arr (global
// end offsets) and scatter col within the bucket's contiguous region.
__global__ __launch_bounds__(256)
void build_kernel(const unsigned int* __restrict__ bdata, const int* __restrict__ gcount,
                  const int* __restrict__ bbase, int* __restrict__ arr,
                  unsigned short* __restrict__ col, int n, int nbuk, int e) {
    int g = blockIdx.y;
    int b = blockIdx.x;
    int M = gcount[g * nbuk + b];
    if (M > CAP) M = CAP;
    int base = bbase[g * nbuk + b];
    const unsigned int* rec = bdata + ((size_t)g * nbuk + b) * CAP;
    __shared__ int deg[NPB];
    __shared__ int cursor[NPB];
    if (threadIdx.x < NPB) deg[threadIdx.x] = 0;
    __syncthreads();
    for (int i = threadIdx.x; i < M; i += 256)
        atomicAdd(&deg[rec[i] >> 16], 1);
    __syncthreads();
    if (threadIdx.x < NPB) {
        int d = deg[threadIdx.x];
        int incl = d;
        #pragma unroll
        for (int off = 1; off < NPB; off <<= 1) {
            int t = __shfl_up(incl, off, 64);
            if ((int)threadIdx.x >= off) incl += t;
        }
        cursor[threadIdx.x] = base + incl - d;   // exclusive start within graph
        int node = b * NPB + threadIdx.x;
        if (node < n) arr[(size_t)g * n + node] = base + incl;   // end offset
    }
    __syncthreads();
    for (int i = threadIdx.x; i < M; i += 256) {
        unsigned int r = rec[i];
        int p = atomicAdd(&cursor[r >> 16], 1);
        if (p < e) col[(size_t)g * e + p] = (unsigned short)(r & 0xFFFF);
    }
}

// ---------------- conversions ----------------

__global__ void f32_to_bf16_kernel(const float* __restrict__ in, unsigned short* __restrict__ out, int n4) {
    int i = blockIdx.x * blockDim.x + threadIdx.x;
    if (i < n4) {
        float4 v = *(const float4*)(in + (size_t)i * 4);
        ushort4 o;
        o.x = f2bf(v.x); o.y = f2bf(v.y); o.z = f2bf(v.z); o.w = f2bf(v.w);
        *(ushort4*)(out + (size_t)i * 4) = o;
    }
}

__global__ void pack_weights_kernel(const float* __restrict__ Wl, const float* __restrict__ Wr,
                                    unsigned short* __restrict__ out) {
    int i = blockIdx.x * blockDim.x + threadIdx.x;   // 128*256
    if (i < 128 * 256) {
        int j = i >> 8, k = i & 255;
        float v = (k < 128) ? Wl[j * 128 + k] : Wr[j * 128 + (k - 128)];
        out[i] = f2bf(v);
    }
}

// ---------------- layer-1 gather-mean: 4 nodes/wave, 16 lanes/node, 8-deep unroll ----------------

__global__ __launch_bounds__(256)
void agg1_kernel(const int* __restrict__ arr, const unsigned short* __restrict__ col,
                 const unsigned short* __restrict__ x, unsigned short* __restrict__ out, int n) {
    int node = (blockIdx.x * 256 + threadIdx.x) >> 4;
    int l = threadIdx.x & 15;
    if (node >= n) return;
    int beg = (node == 0) ? 0 : arr[node - 1];
    int end = arr[node];
    float acc[8] = {0.f, 0.f, 0.f, 0.f, 0.f, 0.f, 0.f, 0.f};
    const unsigned short* xb = x + l * 8;
    int e = beg;
    for (; e + 8 <= end; e += 8) {
        uint4 v[8];
        #pragma unroll
        for (int j = 0; j < 8; ++j)
            v[j] = *(const uint4*)(xb + (size_t)col[e + j] * FD);
        #pragma unroll
        for (int j = 0; j < 8; ++j) add8(acc, v[j]);
    }
    for (; e < end; ++e)
        add8(acc, *(const uint4*)(xb + (size_t)col[e] * FD));
    int deg = end - beg;
    float inv = 1.f / (float)(deg > 1 ? deg : 1);
    uint4 o;
    o.x = pack2(acc[0] * inv, acc[1] * inv);
    o.y = pack2(acc[2] * inv, acc[3] * inv);
    o.z = pack2(acc[4] * inv, acc[5] * inv);
    o.w = pack2(acc[6] * inv, acc[7] * inv);
    *(uint4*)(out + (size_t)node * FD + l * 8) = o;
}

// ---------------- layer-2 gather-mean, fused over 4 time steps: 1 wave/node ----------------

__global__ __launch_bounds__(256)
void agg2_kernel(const int* __restrict__ arr, const unsigned short* __restrict__ col,
                 const unsigned short* __restrict__ ys, unsigned short* __restrict__ out, int n) {
    int node = (blockIdx.x * 256 + threadIdx.x) >> 6;
    int lane = threadIdx.x & 63;
    if (node >= n) return;
    int t = lane >> 4, l = lane & 15;
    int beg = (node == 0) ? 0 : arr[node - 1];
    int end = arr[node];
    float acc[8] = {0.f, 0.f, 0.f, 0.f, 0.f, 0.f, 0.f, 0.f};
    const unsigned short* xb = ys + (size_t)t * n * FD + l * 8;
    int e = beg;
    for (; e + 8 <= end; e += 8) {
        uint4 v[8];
        #pragma unroll
        for (int j = 0; j < 8; ++j)
            v[j] = *(const uint4*)(xb + (size_t)col[e + j] * FD);
        #pragma unroll
        for (int j = 0; j < 8; ++j) add8(acc, v[j]);
    }
    for (; e < end; ++e)
        add8(acc, *(const uint4*)(xb + (size_t)col[e] * FD));
    int deg = end - beg;
    float inv = 1.f / (float)(deg > 1 ? deg : 1);
    uint4 o;
    o.x = pack2(acc[0] * inv, acc[1] * inv);
    o.y = pack2(acc[2] * inv, acc[3] * inv);
    o.z = pack2(acc[4] * inv, acc[5] * inv);
    o.w = pack2(acc[6] * inv, acc[7] * inv);
    *(uint4*)(out + ((size_t)t * n + node) * FD + l * 8) = o;
}

// ---------------- SAGE GEMM layer 1: ys = leaky_relu([Am|Ax] @ Wcat^T + bias) ----------------

__global__ __launch_bounds__(256)
void sage_gemm_kernel(const unsigned short* __restrict__ Am, const unsigned short* __restrict__ Ax,
                      const unsigned short* __restrict__ Wcat, const float* __restrict__ bias,
                      unsigned short* __restrict__ out, int n) {
    int wave = threadIdx.x >> 6;
    int lane = threadIdx.x & 63;
    int m = lane & 15, q = lane >> 4;
    int rowBase = blockIdx.x * 64 + wave * 16;
    int arow = rowBase + m;
    if (arow >= n) arow = n - 1;

    f32x4 acc[8];
    #pragma unroll
    for (int i = 0; i < 8; ++i) acc[i] = (f32x4){0.f, 0.f, 0.f, 0.f};

    #pragma unroll
    for (int step = 0; step < 8; ++step) {
        const unsigned short* Asrc = (step < 4) ? Am : Ax;
        int ka = (step & 3) * 32 + q * 8;
        bf16x8 afrag = *(const bf16x8*)(Asrc + (size_t)arow * FD + ka);
        int kw = step * 32 + q * 8;
        #pragma unroll
        for (int ct = 0; ct < 8; ++ct) {
            bf16x8 bfrag = *(const bf16x8*)(Wcat + (ct * 16 + m) * 256 + kw);
            acc[ct] = __builtin_amdgcn_mfma_f32_16x16x32_bf16(afrag, bfrag, acc[ct], 0, 0, 0);
        }
    }

    #pragma unroll
    for (int ct = 0; ct < 8; ++ct) {
        int colc = ct * 16 + m;
        float b = bias[colc];
        #pragma unroll
        for (int r = 0; r < 4; ++r) {
            int row = rowBase + q * 4 + r;
            if (row < n) {
                float v = acc[ct][r] + b;
                v = (v >= 0.f) ? v : 0.2f * v;
                out[(size_t)row * FD + colc] = f2bf(v);
            }
        }
    }
}

// ---------------- SAGE GEMM layer 2 fused with classifier ----------------

__global__ __launch_bounds__(256)
void gemm2_cls_kernel(const unsigned short* __restrict__ Am, const unsigned short* __restrict__ Ax,
                      const unsigned short* __restrict__ Wcat, const float* __restrict__ bias,
                      const float* __restrict__ Wc, const float* __restrict__ bc,
                      float* __restrict__ logits, int mrows) {
    int wave = threadIdx.x >> 6;
    int lane = threadIdx.x & 63;
    int m = lane & 15, q = lane >> 4;
    int rowBase = blockIdx.x * 64 + wave * 16;
    int arow = rowBase + m;
    if (arow >= mrows) arow = mrows - 1;

    f32x4 acc[8];
    #pragma unroll
    for (int i = 0; i < 8; ++i) acc[i] = (f32x4){0.f, 0.f, 0.f, 0.f};

    #pragma unroll
    for (int step = 0; step < 8; ++step) {
        const unsigned short* Asrc = (step < 4) ? Am : Ax;
        int ka = (step & 3) * 32 + q * 8;
        bf16x8 afrag = *(const bf16x8*)(Asrc + (size_t)arow * FD + ka);
        int kw = step * 32 + q * 8;
        #pragma unroll
        for (int ct = 0; ct < 8; ++ct) {
            bf16x8 bfrag = *(const bf16x8*)(Wcat + (ct * 16 + m) * 256 + kw);
            acc[ct] = __builtin_amdgcn_mfma_f32_16x16x32_bf16(afrag, bfrag, acc[ct], 0, 0, 0);
        }
    }

    float wc0[8], wc1[8], bb[8];
    #pragma unroll
    for (int ct = 0; ct < 8; ++ct) {
        wc0[ct] = Wc[ct * 16 + m];
        wc1[ct] = Wc[FD + ct * 16 + m];
        bb[ct]  = bias[ct * 16 + m];
    }
    float bc0 = bc[0], bc1 = bc[1];

    #pragma unroll
    for (int r = 0; r < 4; ++r) {
        float p0 = 0.f, p1 = 0.f;
        #pragma unroll
        for (int ct = 0; ct < 8; ++ct) {
            float v = acc[ct][r] + bb[ct];
            v = (v >= 0.f) ? v : 0.2f * v;
            p0 += v * wc0[ct];
            p1 += v * wc1[ct];
        }
        #pragma unroll
        for (int off = 8; off > 0; off >>= 1) {
            p0 += __shfl_down(p0, off);
            p1 += __shfl_down(p1, off);
        }
        if (m == 0) {
            int row = rowBase + q * 4 + r;
            if (row < mrows) {
                logits[(size_t)row * CC]     = p0 + bc0;
                logits[(size_t)row * CC + 1] = p1 + bc1;
            }
        }
    }
}

// ---------------- log_softmax over node axis (2-stage online) ----------------

__global__ __launch_bounds__(256)
void lse_partial_kernel(const float* __restrict__ logits, float* __restrict__ pm,
                        float* __restrict__ ps, int n) {
    int tc = blockIdx.y;
    int t = tc >> 1, c = tc & 1;
    const float* p = logits + (size_t)t * n * CC + c;
    float m = -1e30f, s = 0.f;
    for (int i = blockIdx.x * 256 + threadIdx.x; i < n; i += LSE_CH * 256) {
        float v = p[(size_t)i * CC];
        if (v > m) { s = s * __expf(m - v) + 1.f; m = v; }
        else s += __expf(v - m);
    }
    __shared__ float smm[256], sms[256];
    smm[threadIdx.x] = m; sms[threadIdx.x] = s;
    __syncthreads();
    for (int off = 128; off > 0; off >>= 1) {
        if (threadIdx.x < off) {
            float m2 = smm[threadIdx.x + off], s2 = sms[threadIdx.x + off];
            float M = fmaxf(smm[threadIdx.x], m2);
            sms[threadIdx.x] = sms[threadIdx.x] * __expf(smm[threadIdx.x] - M) + s2 * __expf(m2 - M);
            smm[threadIdx.x] = M;
        }
        __syncthreads();
    }
    if (threadIdx.x == 0) { pm[tc * LSE_CH + blockIdx.x] = smm[0]; ps[tc * LSE_CH + blockIdx.x] = sms[0]; }
}

__global__ void lse_final_kernel(const float* __restrict__ pm, const float* __restrict__ ps,
                                 float* __restrict__ lse) {
    int tc = blockIdx.x;
    int lane = threadIdx.x;
    float m = (lane < LSE_CH) ? pm[tc * LSE_CH + lane] : -1e30f;
    float s = (lane < LSE_CH) ? ps[tc * LSE_CH + lane] : 0.f;
    #pragma unroll
    for (int off = 32; off > 0; off >>= 1) {
        float m2 = __shfl_down(m, off);
        float s2 = __shfl_down(s, off);
        float M = fmaxf(m, m2);
        s = s * __expf(m - M) + s2 * __expf(m2 - M);
        m = M;
    }
    if (lane == 0) lse[tc] = m + logf(s);
}

__global__ void sub_lse_kernel(const float* __restrict__ logits, const float* __restrict__ lse,
                               float* __restrict__ out, int total, int n) {
    int i = blockIdx.x * blockDim.x + threadIdx.x;
    if (i < total) {
        int c = i & 1;
        int t = i / (n * CC);
        out[i] = logits[i] - lse[t * CC + c];
    }
}

// ---------------- launch ----------------

extern "C" void kernel_launch(void* const* d_in, const int* in_sizes, int n_in,
                              void* d_out, int out_size, void* d_ws, size_t ws_size,
                              hipStream_t stream) {
    const int* graph = (const int*)d_in[0];
    const float* fts = (const float*)d_in[1];
    const float* W1l = (const float*)d_in[3];
    const float* b1  = (const float*)d_in[4];
    const float* W1r = (const float*)d_in[5];
    const float* W2l = (const float*)d_in[6];
    const float* b2  = (const float*)d_in[7];
    const float* W2r = (const float*)d_in[8];
    const float* Wc  = (const float*)d_in[9];
    const float* bc  = (const float*)d_in[10];
    float* out = (float*)d_out;

    const int T = TT;
    const int E = in_sizes[0] / (T * 2);
    const int N = in_sizes[1] / (T * FD);
    const int NBUK = (N + NPB - 1) >> NPB_SHIFT;     // 782 <= 1024

    size_t off = 0;
    auto alloc = [&](size_t bytes) -> char* {
        char* p = (char*)d_ws + off;
        off += (bytes + 511) & ~(size_t)511;
        return p;
    };
    int* arr_all = (int*)alloc((size_t)T * N * 4);
    unsigned short* col_all = (unsigned short*)alloc((size_t)T * E * 2);
    int* gcount = (int*)alloc((size_t)T * NBUK * 4);
    int* bbase  = (int*)alloc((size_t)T * NBUK * 4);
    unsigned short* ysall = (unsigned short*)alloc((size_t)T * N * FD * 2);
    unsigned short* wcat1 = (unsigned short*)alloc(128 * 256 * 2);
    unsigned short* wcat2 = (unsigned short*)alloc(128 * 256 * 2);
    float* logits = (float*)alloc((size_t)T * N * CC * 4);
    float* pm  = (float*)alloc((size_t)T * CC * LSE_CH * 4);
    float* ps  = (float*)alloc((size_t)T * CC * LSE_CH * 4);
    float* lse = (float*)alloc(T * CC * 4);
    // scratch region, multiply aliased (phases are strictly ordered):
    //   CSR build: bdata (T*NBUK*CAP*4 = 19.2 MB)
    //   layer 1:   xbf + mean1 (2 * N*FD*2)
    //   layer 2:   mean2all (T * N*FD*2 = 51.2 MB)
    unsigned short* scratch = (unsigned short*)alloc((size_t)T * N * FD * 2);
    unsigned int* bdata = (unsigned int*)scratch;
    unsigned short* xbf   = scratch;
    unsigned short* mean1 = scratch + (size_t)N * FD;
    unsigned short* mean2all = scratch;

    pack_weights_kernel<<<(128 * 256 + 255) / 256, 256, 0, stream>>>(W1l, W1r, wcat1);
    pack_weights_kernel<<<(128 * 256 + 255) / 256, 256, 0, stream>>>(W2l, W2r, wcat2);

    // CSR build via binning
    hipMemsetAsync(gcount, 0, (size_t)T * NBUK * 4, stream);
    dim3 bingrid((E + BIN_TILE - 1) / BIN_TILE, T);
    bin_kernel<<<bingrid, 256, 0, stream>>>(graph, gcount, bdata, E, NBUK);
    bucket_scan_kernel<<<T, 1024, 0, stream>>>(gcount, bbase, NBUK);
    dim3 buildgrid(NBUK, T);
    build_kernel<<<buildgrid, 256, 0, stream>>>(bdata, gcount, bbase, arr_all, col_all, N, NBUK, E);
    // arr_all[g][i] = end offset of node i; beg = arr_all[g][i-1] (0 for i==0)

    const int aggBlocks  = (N * 16 + 255) / 256;
    const int wavBlocks  = (N * 64 + 255) / 256;
    const int gemmBlocks = (N + 63) / 64;
    const int* arrL = arr_all + (size_t)(T - 1) * N;
    const unsigned short* colL = col_all + (size_t)(T - 1) * E;

    // layer 1 per time step
    for (int t = 0; t < T; ++t) {
        f32_to_bf16_kernel<<<((N * FD / 4) + 255) / 256, 256, 0, stream>>>(
            fts + (size_t)t * N * FD, xbf, N * FD / 4);
        agg1_kernel<<<aggBlocks, 256, 0, stream>>>(arr_all + (size_t)t * N,
                                                   col_all + (size_t)t * E, xbf, mean1, N);
        sage_gemm_kernel<<<gemmBlocks, 256, 0, stream>>>(mean1, xbf, wcat1, b1,
                                                         ysall + (size_t)t * N * FD, N);
    }

    // layer 2: fused aggregation over 4 t's (last graph), then fused GEMM+classifier
    agg2_kernel<<<wavBlocks, 256, 0, stream>>>(arrL, colL, ysall, mean2all, N);
    int mrows = T * N;
    gemm2_cls_kernel<<<(mrows + 63) / 64, 256, 0, stream>>>(mean2all, ysall, wcat2, b2,
                                                            Wc, bc, logits, mrows);

    dim3 lgrid(LSE_CH, T * CC);
    lse_partial_kernel<<<lgrid, 256, 0, stream>>>(logits, pm, ps, N);
    lse_final_kernel<<<T * CC, 64, 0, stream>>>(pm, ps, lse);
    int total = T * N * CC;
    sub_lse_kernel<<<(total + 255) / 256, 256, 0, stream>>>(logits, lse, out, total, N);
}

// Round 5
// 725.254 us; speedup vs baseline: 2.1866x; 1.0916x over previous
//
#include <hip/hip_runtime.h>
#include <hip/hip_bf16.h>

#define TT 4
#define FD 128          // F_IN == H == O == 128
#define FD4 512         // interleaved row: 4 t-slices of 128
#define CC 2
#define LSE_CH 32

// binning parameters
#define NPB 64
#define NPB_SHIFT 6
#define NBUKMAX 1024    // ceil(50000/64) = 782 <= 1024
#define CAP 1536
#define BIN_TILE 8192

typedef __attribute__((ext_vector_type(8))) short bf16x8;
typedef __attribute__((ext_vector_type(4))) float f32x4;

__device__ __forceinline__ float bf2f(unsigned int h) {
    union { unsigned int u; float f; } v; v.u = h << 16; return v.f;
}
__device__ __forceinline__ unsigned short f2bf(float f) {
    union { float f; unsigned int u; } v; v.f = f;
    unsigned int u = v.u;
    unsigned int r = u + 0x7FFFu + ((u >> 16) & 1u);   // round-to-nearest-even
    return (unsigned short)(r >> 16);
}
__device__ __forceinline__ unsigned int pack2(float lo, float hi) {
    return ((unsigned int)f2bf(hi) << 16) | (unsigned int)f2bf(lo);
}
__device__ __forceinline__ void add8(float* a, uint4 v) {
    a[0] += bf2f(v.x & 0xFFFF); a[1] += bf2f(v.x >> 16);
    a[2] += bf2f(v.y & 0xFFFF); a[3] += bf2f(v.y >> 16);
    a[4] += bf2f(v.z & 0xFFFF); a[5] += bf2f(v.z >> 16);
    a[6] += bf2f(v.w & 0xFFFF); a[7] += bf2f(v.w >> 16);
}

// ---------------- CSR build via two-level binning ----------------

__global__ __launch_bounds__(256)
void bin_kernel(const int* __restrict__ graph, int* __restrict__ gcount,
                unsigned int* __restrict__ bdata, int e, int nbuk) {
    int g = blockIdx.y;
    const int* src = graph + (size_t)g * 2 * e;
    const int* dst = src + e;
    int tbeg = blockIdx.x * BIN_TILE;
    int tend = tbeg + BIN_TILE < e ? tbeg + BIN_TILE : e;
    __shared__ int cnt[NBUKMAX];
    __shared__ int base[NBUKMAX];
    for (int i = threadIdx.x; i < nbuk; i += 256) cnt[i] = 0;
    __syncthreads();
    for (int i = tbeg + threadIdx.x; i < tend; i += 256)
        atomicAdd(&cnt[dst[i] >> NPB_SHIFT], 1);
    __syncthreads();
    for (int i = threadIdx.x; i < nbuk; i += 256) {
        int c = cnt[i];
        base[i] = (c > 0) ? atomicAdd(&gcount[g * nbuk + i], c) : 0;
        cnt[i] = 0;                         // reuse as cursor
    }
    __syncthreads();
    for (int i = tbeg + threadIdx.x; i < tend; i += 256) {
        int d = dst[i];
        int b = d >> NPB_SHIFT;
        int pos = base[b] + atomicAdd(&cnt[b], 1);
        if (pos < CAP)
            bdata[((size_t)g * nbuk + b) * CAP + pos] =
                ((unsigned int)(d & (NPB - 1)) << 16) | (unsigned int)src[i];
    }
}

__global__ __launch_bounds__(1024)
void bucket_scan_kernel(const int* __restrict__ gcount, int* __restrict__ bbase, int nbuk) {
    int g = blockIdx.x;
    __shared__ int sm[1024];
    int v = (threadIdx.x < nbuk) ? gcount[g * nbuk + threadIdx.x] : 0;
    sm[threadIdx.x] = v;
    __syncthreads();
    #pragma unroll
    for (int off = 1; off < 1024; off <<= 1) {
        int t = (threadIdx.x >= off) ? sm[threadIdx.x - off] : 0;
        __syncthreads();
        sm[threadIdx.x] += t;
        __syncthreads();
    }
    if (threadIdx.x < nbuk) bbase[g * nbuk + threadIdx.x] = sm[threadIdx.x] - v;
}

__global__ __launch_bounds__(256)
void build_kernel(const unsigned int* __restrict__ bdata, const int* __restrict__ gcount,
                  const int* __restrict__ bbase, int* __restrict__ arr,
                  unsigned short* __restrict__ col, int n, int nbuk, int e) {
    int g = blockIdx.y;
    int b = blockIdx.x;
    int M = gcount[g * nbuk + b];
    if (M > CAP) M = CAP;
    int base = bbase[g * nbuk + b];
    const unsigned int* rec = bdata + ((size_t)g * nbuk + b) * CAP;
    __shared__ int deg[NPB];
    __shared__ int cursor[NPB];
    if (threadIdx.x < NPB) deg[threadIdx.x] = 0;
    __syncthreads();
    for (int i = threadIdx.x; i < M; i += 256)
        atomicAdd(&deg[rec[i] >> 16], 1);
    __syncthreads();
    if (threadIdx.x < NPB) {
        int d = deg[threadIdx.x];
        int incl = d;
        #pragma unroll
        for (int off = 1; off < NPB; off <<= 1) {
            int t = __shfl_up(incl, off, 64);
            if ((int)threadIdx.x >= off) incl += t;
        }
        cursor[threadIdx.x] = base + incl - d;
        int node = b * NPB + threadIdx.x;
        if (node < n) arr[(size_t)g * n + node] = base + incl;   // end offset
    }
    __syncthreads();
    for (int i = threadIdx.x; i < M; i += 256) {
        unsigned int r = rec[i];
        int p = atomicAdd(&cursor[r >> 16], 1);
        if (p < e) col[(size_t)g * e + p] = (unsigned short)(r & 0xFFFF);
    }
}

// ---------------- conversion: fts [t][node][128] f32 -> xI [node][t][128] bf16 ----------------

__global__ __launch_bounds__(256)
void conv_kernel(const float* __restrict__ fts, unsigned short* __restrict__ xI,
                 int n, int total16) {
    int tid = blockIdx.x * 256 + threadIdx.x;
    if (tid >= total16) return;                 // total16 = T*N*16
    int k = tid & 15;
    int nt = tid >> 4;                          // t*n + node
    int t = nt / n;
    int node = nt - t * n;
    const float* s = fts + (size_t)nt * FD + k * 8;
    float4 a = *(const float4*)s;
    float4 b = *(const float4*)(s + 4);
    uint4 o;
    o.x = pack2(a.x, a.y); o.y = pack2(a.z, a.w);
    o.z = pack2(b.x, b.y); o.w = pack2(b.z, b.w);
    *(uint4*)(xI + (size_t)node * FD4 + t * FD + k * 8) = o;
}

__global__ void pack_weights_kernel(const float* __restrict__ Wl, const float* __restrict__ Wr,
                                    unsigned short* __restrict__ out) {
    int i = blockIdx.x * blockDim.x + threadIdx.x;   // 128*256
    if (i < 128 * 256) {
        int j = i >> 8, k = i & 255;
        float v = (k < 128) ? Wl[j * 128 + k] : Wr[j * 128 + (k - 128)];
        out[i] = f2bf(v);
    }
}

// ---------------- layer-1 gather-mean, batched over graphs: blockIdx.y = t ----------------
// 4 nodes/wave, 16 lanes/node; gathers 256 B from xI[src][t][.]; writes mean1I[node][t][.]

__global__ __launch_bounds__(256)
void agg1_kernel(const int* __restrict__ arr_all, const unsigned short* __restrict__ col_all,
                 const unsigned short* __restrict__ xI, unsigned short* __restrict__ mean1I,
                 int n, int e) {
    int g = blockIdx.y;
    int node = (blockIdx.x * 256 + threadIdx.x) >> 4;
    int l = threadIdx.x & 15;
    if (node >= n) return;
    const int* arr = arr_all + (size_t)g * n;
    const unsigned short* col = col_all + (size_t)g * e;
    int beg = (node == 0) ? 0 : arr[node - 1];
    int end = arr[node];
    float acc[8] = {0.f, 0.f, 0.f, 0.f, 0.f, 0.f, 0.f, 0.f};
    const unsigned short* xb = xI + g * FD + l * 8;
    int ed = beg;
    for (; ed + 8 <= end; ed += 8) {
        uint4 v[8];
        #pragma unroll
        for (int j = 0; j < 8; ++j)
            v[j] = *(const uint4*)(xb + (size_t)col[ed + j] * FD4);
        #pragma unroll
        for (int j = 0; j < 8; ++j) add8(acc, v[j]);
    }
    for (; ed < end; ++ed)
        add8(acc, *(const uint4*)(xb + (size_t)col[ed] * FD4));
    int deg = end - beg;
    float inv = 1.f / (float)(deg > 1 ? deg : 1);
    uint4 o;
    o.x = pack2(acc[0] * inv, acc[1] * inv);
    o.y = pack2(acc[2] * inv, acc[3] * inv);
    o.z = pack2(acc[4] * inv, acc[5] * inv);
    o.w = pack2(acc[6] * inv, acc[7] * inv);
    *(uint4*)(mean1I + (size_t)node * FD4 + g * FD + l * 8) = o;
}

// ---------------- layer-2 gather-mean: 1 wave/node, contiguous 1 KB per edge ----------------

__global__ __launch_bounds__(256)
void agg2_kernel(const int* __restrict__ arr, const unsigned short* __restrict__ col,
                 const unsigned short* __restrict__ ysI, unsigned short* __restrict__ mean2I,
                 int n) {
    int node = (blockIdx.x * 256 + threadIdx.x) >> 6;
    int lane = threadIdx.x & 63;
    if (node >= n) return;
    int beg = (node == 0) ? 0 : arr[node - 1];
    int end = arr[node];
    float acc[8] = {0.f, 0.f, 0.f, 0.f, 0.f, 0.f, 0.f, 0.f};
    const unsigned short* xb = ysI + lane * 8;
    int e = beg;
    for (; e + 8 <= end; e += 8) {
        uint4 v[8];
        #pragma unroll
        for (int j = 0; j < 8; ++j)
            v[j] = *(const uint4*)(xb + (size_t)col[e + j] * FD4);
        #pragma unroll
        for (int j = 0; j < 8; ++j) add8(acc, v[j]);
    }
    for (; e < end; ++e)
        add8(acc, *(const uint4*)(xb + (size_t)col[e] * FD4));
    int deg = end - beg;
    float inv = 1.f / (float)(deg > 1 ? deg : 1);
    uint4 o;
    o.x = pack2(acc[0] * inv, acc[1] * inv);
    o.y = pack2(acc[2] * inv, acc[3] * inv);
    o.z = pack2(acc[4] * inv, acc[5] * inv);
    o.w = pack2(acc[6] * inv, acc[7] * inv);
    *(uint4*)(mean2I + (size_t)node * FD4 + lane * 8) = o;
}

// ---------------- SAGE GEMM: out = leaky_relu([Am|Ax] @ Wcat^T + bias) ----------------
// rows = [4N][128] interleaved matrices; out may alias Am (each wave reads only its own
// 16 rows before writing them). NOTE: no __restrict__ on Am/out (they alias for layer 1).

__global__ __launch_bounds__(256)
void sage_gemm_kernel(const unsigned short* Am, const unsigned short* __restrict__ Ax,
                      const unsigned short* __restrict__ Wcat, const float* __restrict__ bias,
                      unsigned short* out, int mrows) {
    int wave = threadIdx.x >> 6;
    int lane = threadIdx.x & 63;
    int m = lane & 15, q = lane >> 4;
    int rowBase = blockIdx.x * 64 + wave * 16;
    int arow = rowBase + m;
    if (arow >= mrows) arow = mrows - 1;

    f32x4 acc[8];
    #pragma unroll
    for (int i = 0; i < 8; ++i) acc[i] = (f32x4){0.f, 0.f, 0.f, 0.f};

    #pragma unroll
    for (int step = 0; step < 8; ++step) {
        const unsigned short* Asrc = (step < 4) ? Am : Ax;
        int ka = (step & 3) * 32 + q * 8;
        bf16x8 afrag = *(const bf16x8*)(Asrc + (size_t)arow * FD + ka);
        int kw = step * 32 + q * 8;
        #pragma unroll
        for (int ct = 0; ct < 8; ++ct) {
            bf16x8 bfrag = *(const bf16x8*)(Wcat + (ct * 16 + m) * 256 + kw);
            acc[ct] = __builtin_amdgcn_mfma_f32_16x16x32_bf16(afrag, bfrag, acc[ct], 0, 0, 0);
        }
    }

    #pragma unroll
    for (int ct = 0; ct < 8; ++ct) {
        int colc = ct * 16 + m;
        float b = bias[colc];
        #pragma unroll
        for (int r = 0; r < 4; ++r) {
            int row = rowBase + q * 4 + r;
            if (row < mrows) {
                float v = acc[ct][r] + b;
                v = (v >= 0.f) ? v : 0.2f * v;
                out[(size_t)row * FD + colc] = f2bf(v);
            }
        }
    }
}

// ---------------- layer-2 GEMM fused with classifier (interleaved rows -> [t][node][c]) ----

__global__ __launch_bounds__(256)
void gemm2_cls_kernel(const unsigned short* __restrict__ Am, const unsigned short* __restrict__ Ax,
                      const unsigned short* __restrict__ Wcat, const float* __restrict__ bias,
                      const float* __restrict__ Wc, const float* __restrict__ bc,
                      float* __restrict__ logits, int mrows, int nnode) {
    int wave = threadIdx.x >> 6;
    int lane = threadIdx.x & 63;
    int m = lane & 15, q = lane >> 4;
    int rowBase = blockIdx.x * 64 + wave * 16;
    int arow = rowBase + m;
    if (arow >= mrows) arow = mrows - 1;

    f32x4 acc[8];
    #pragma unroll
    for (int i = 0; i < 8; ++i) acc[i] = (f32x4){0.f, 0.f, 0.f, 0.f};

    #pragma unroll
    for (int step = 0; step < 8; ++step) {
        const unsigned short* Asrc = (step < 4) ? Am : Ax;
        int ka = (step & 3) * 32 + q * 8;
        bf16x8 afrag = *(const bf16x8*)(Asrc + (size_t)arow * FD + ka);
        int kw = step * 32 + q * 8;
        #pragma unroll
        for (int ct = 0; ct < 8; ++ct) {
            bf16x8 bfrag = *(const bf16x8*)(Wcat + (ct * 16 + m) * 256 + kw);
            acc[ct] = __builtin_amdgcn_mfma_f32_16x16x32_bf16(afrag, bfrag, acc[ct], 0, 0, 0);
        }
    }

    float wc0[8], wc1[8], bb[8];
    #pragma unroll
    for (int ct = 0; ct < 8; ++ct) {
        wc0[ct] = Wc[ct * 16 + m];
        wc1[ct] = Wc[FD + ct * 16 + m];
        bb[ct]  = bias[ct * 16 + m];
    }
    float bc0 = bc[0], bc1 = bc[1];

    #pragma unroll
    for (int r = 0; r < 4; ++r) {
        float p0 = 0.f, p1 = 0.f;
        #pragma unroll
        for (int ct = 0; ct < 8; ++ct) {
            float v = acc[ct][r] + bb[ct];
            v = (v >= 0.f) ? v : 0.2f * v;
            p0 += v * wc0[ct];
            p1 += v * wc1[ct];
        }
        #pragma unroll
        for (int off = 8; off > 0; off >>= 1) {
            p0 += __shfl_down(p0, off);
            p1 += __shfl_down(p1, off);
        }
        if (m == 0) {
            int row = rowBase + q * 4 + r;
            if (row < mrows) {
                int node = row >> 2, t = row & 3;
                size_t base = ((size_t)t * nnode + node) * CC;
                logits[base]     = p0 + bc0;
                logits[base + 1] = p1 + bc1;
            }
        }
    }
}

// ---------------- log_softmax over node axis (2-stage online) ----------------

__global__ __launch_bounds__(256)
void lse_partial_kernel(const float* __restrict__ logits, float* __restrict__ pm,
                        float* __restrict__ ps, int n) {
    int tc = blockIdx.y;
    int t = tc >> 1, c = tc & 1;
    const float* p = logits + (size_t)t * n * CC + c;
    float m = -1e30f, s = 0.f;
    for (int i = blockIdx.x * 256 + threadIdx.x; i < n; i += LSE_CH * 256) {
        float v = p[(size_t)i * CC];
        if (v > m) { s = s * __expf(m - v) + 1.f; m = v; }
        else s += __expf(v - m);
    }
    __shared__ float smm[256], sms[256];
    smm[threadIdx.x] = m; sms[threadIdx.x] = s;
    __syncthreads();
    for (int off = 128; off > 0; off >>= 1) {
        if (threadIdx.x < off) {
            float m2 = smm[threadIdx.x + off], s2 = sms[threadIdx.x + off];
            float M = fmaxf(smm[threadIdx.x], m2);
            sms[threadIdx.x] = sms[threadIdx.x] * __expf(smm[threadIdx.x] - M) + s2 * __expf(m2 - M);
            smm[threadIdx.x] = M;
        }
        __syncthreads();
    }
    if (threadIdx.x == 0) { pm[tc * LSE_CH + blockIdx.x] = smm[0]; ps[tc * LSE_CH + blockIdx.x] = sms[0]; }
}

__global__ void lse_final_kernel(const float* __restrict__ pm, const float* __restrict__ ps,
                                 float* __restrict__ lse) {
    int tc = blockIdx.x;
    int lane = threadIdx.x;
    float m = (lane < LSE_CH) ? pm[tc * LSE_CH + lane] : -1e30f;
    float s = (lane < LSE_CH) ? ps[tc * LSE_CH + lane] : 0.f;
    #pragma unroll
    for (int off = 32; off > 0; off >>= 1) {
        float m2 = __shfl_down(m, off);
        float s2 = __shfl_down(s, off);
        float M = fmaxf(m, m2);
        s = s * __expf(m - M) + s2 * __expf(m2 - M);
        m = M;
    }
    if (lane == 0) lse[tc] = m + logf(s);
}

__global__ void sub_lse_kernel(const float* __restrict__ logits, const float* __restrict__ lse,
                               float* __restrict__ out, int total, int n) {
    int i = blockIdx.x * blockDim.x + threadIdx.x;
    if (i < total) {
        int c = i & 1;
        int t = i / (n * CC);
        out[i] = logits[i] - lse[t * CC + c];
    }
}

// ---------------- launch ----------------

extern "C" void kernel_launch(void* const* d_in, const int* in_sizes, int n_in,
                              void* d_out, int out_size, void* d_ws, size_t ws_size,
                              hipStream_t stream) {
    const int* graph = (const int*)d_in[0];
    const float* fts = (const float*)d_in[1];
    const float* W1l = (const float*)d_in[3];
    const float* b1  = (const float*)d_in[4];
    const float* W1r = (const float*)d_in[5];
    const float* W2l = (const float*)d_in[6];
    const float* b2  = (const float*)d_in[7];
    const float* W2r = (const float*)d_in[8];
    const float* Wc  = (const float*)d_in[9];
    const float* bc  = (const float*)d_in[10];
    float* out = (float*)d_out;

    const int T = TT;
    const int E = in_sizes[0] / (T * 2);
    const int N = in_sizes[1] / (T * FD);
    const int NBUK = (N + NPB - 1) >> NPB_SHIFT;

    size_t off = 0;
    auto alloc = [&](size_t bytes) -> char* {
        char* p = (char*)d_ws + off;
        off += (bytes + 511) & ~(size_t)511;
        return p;
    };
    int* arr_all = (int*)alloc((size_t)T * N * 4);
    unsigned short* col_all = (unsigned short*)alloc((size_t)T * E * 2);
    int* gcount = (int*)alloc((size_t)T * NBUK * 4);
    int* bbase  = (int*)alloc((size_t)T * NBUK * 4);
    unsigned short* wcat1 = (unsigned short*)alloc(128 * 256 * 2);
    unsigned short* wcat2 = (unsigned short*)alloc(128 * 256 * 2);
    float* logits = (float*)alloc((size_t)T * N * CC * 4);
    float* pm  = (float*)alloc((size_t)T * CC * LSE_CH * 4);
    float* ps  = (float*)alloc((size_t)T * CC * LSE_CH * 4);
    float* lse = (float*)alloc(T * CC * 4);
    // R1: bdata (CSR build) -> xI (conv..gemm1) -> mean2I (agg2..gemm2).  51.2 MB
    // R2: mean1I (agg1) -> ysI in-place (gemm1..gemm2).                   51.2 MB
    unsigned short* R1 = (unsigned short*)alloc((size_t)N * FD4 * 2);
    unsigned short* R2 = (unsigned short*)alloc((size_t)N * FD4 * 2);
    unsigned int* bdata = (unsigned int*)R1;
    unsigned short* xI = R1;
    unsigned short* mean2I = R1;
    unsigned short* mean1I = R2;
    unsigned short* ysI = R2;

    pack_weights_kernel<<<(128 * 256 + 255) / 256, 256, 0, stream>>>(W1l, W1r, wcat1);
    pack_weights_kernel<<<(128 * 256 + 255) / 256, 256, 0, stream>>>(W2l, W2r, wcat2);

    // CSR build (uses R1 as bdata — must precede conv)
    hipMemsetAsync(gcount, 0, (size_t)T * NBUK * 4, stream);
    dim3 bingrid((E + BIN_TILE - 1) / BIN_TILE, T);
    bin_kernel<<<bingrid, 256, 0, stream>>>(graph, gcount, bdata, E, NBUK);
    bucket_scan_kernel<<<T, 1024, 0, stream>>>(gcount, bbase, NBUK);
    dim3 buildgrid(NBUK, T);
    build_kernel<<<buildgrid, 256, 0, stream>>>(bdata, gcount, bbase, arr_all, col_all, N, NBUK, E);

    // conversion (overwrites R1 with xI)
    int total16 = T * N * 16;
    conv_kernel<<<(total16 + 255) / 256, 256, 0, stream>>>(fts, xI, N, total16);

    // layer 1: batched aggregation (4 graphs), then one 4N-row GEMM in-place
    dim3 agg1grid((N * 16 + 255) / 256, T);
    agg1_kernel<<<agg1grid, 256, 0, stream>>>(arr_all, col_all, xI, mean1I, N, E);
    int mrows = T * N;
    sage_gemm_kernel<<<(mrows + 63) / 64, 256, 0, stream>>>(mean1I, xI, wcat1, b1, ysI, mrows);

    // layer 2: aggregation with last graph (1 KB contiguous gathers), fused GEMM+classifier
    const int* arrL = arr_all + (size_t)(T - 1) * N;
    const unsigned short* colL = col_all + (size_t)(T - 1) * E;
    agg2_kernel<<<(N * 64 + 255) / 256, 256, 0, stream>>>(arrL, colL, ysI, mean2I, N);
    gemm2_cls_kernel<<<(mrows + 63) / 64, 256, 0, stream>>>(mean2I, ysI, wcat2, b2,
                                                            Wc, bc, logits, mrows, N);

    dim3 lgrid(LSE_CH, T * CC);
    lse_partial_kernel<<<lgrid, 256, 0, stream>>>(logits, pm, ps, N);
    lse_final_kernel<<<T * CC, 64, 0, stream>>>(pm, ps, lse);
    int total = T * N * CC;
    sub_lse_kernel<<<(total + 255) / 256, 256, 0, stream>>>(logits, lse, out, total, N);
}

// Round 6
// 583.255 us; speedup vs baseline: 2.7190x; 1.2435x over previous
//
#include <hip/hip_runtime.h>
#include <hip/hip_bf16.h>

#define TT 4
#define FD 128          // F_IN == H == O == 128
#define FD4 512         // interleaved row: 4 t-slices of 128
#define CC 2
#define LSE_CH 32
#define WROW 264        // padded LDS row stride (elems): 528 B -> 4-bank shift/row

// binning parameters
#define NPB 64
#define NPB_SHIFT 6
#define NBUKMAX 1024
#define CAP 1536
#define BIN_TILE 8192

typedef __attribute__((ext_vector_type(8))) short bf16x8;
typedef __attribute__((ext_vector_type(4))) float f32x4;

__device__ __forceinline__ float bf2f(unsigned int h) {
    union { unsigned int u; float f; } v; v.u = h << 16; return v.f;
}
__device__ __forceinline__ unsigned short f2bf(float f) {
    union { float f; unsigned int u; } v; v.f = f;
    unsigned int u = v.u;
    unsigned int r = u + 0x7FFFu + ((u >> 16) & 1u);   // round-to-nearest-even
    return (unsigned short)(r >> 16);
}
__device__ __forceinline__ unsigned int pack2(float lo, float hi) {
    return ((unsigned int)f2bf(hi) << 16) | (unsigned int)f2bf(lo);
}
__device__ __forceinline__ void add8(float* a, uint4 v) {
    a[0] += bf2f(v.x & 0xFFFF); a[1] += bf2f(v.x >> 16);
    a[2] += bf2f(v.y & 0xFFFF); a[3] += bf2f(v.y >> 16);
    a[4] += bf2f(v.z & 0xFFFF); a[5] += bf2f(v.z >> 16);
    a[6] += bf2f(v.w & 0xFFFF); a[7] += bf2f(v.w >> 16);
}

// ---------------- CSR build via two-level binning ----------------

__global__ __launch_bounds__(256)
void bin_kernel(const int* __restrict__ graph, int* __restrict__ gcount,
                unsigned int* __restrict__ bdata, int e, int nbuk) {
    int g = blockIdx.y;
    const int* src = graph + (size_t)g * 2 * e;
    const int* dst = src + e;
    int tbeg = blockIdx.x * BIN_TILE;
    int tend = tbeg + BIN_TILE < e ? tbeg + BIN_TILE : e;
    __shared__ int cnt[NBUKMAX];
    __shared__ int base[NBUKMAX];
    for (int i = threadIdx.x; i < nbuk; i += 256) cnt[i] = 0;
    __syncthreads();
    for (int i = tbeg + threadIdx.x; i < tend; i += 256)
        atomicAdd(&cnt[dst[i] >> NPB_SHIFT], 1);
    __syncthreads();
    for (int i = threadIdx.x; i < nbuk; i += 256) {
        int c = cnt[i];
        base[i] = (c > 0) ? atomicAdd(&gcount[g * nbuk + i], c) : 0;
        cnt[i] = 0;                         // reuse as cursor
    }
    __syncthreads();
    for (int i = tbeg + threadIdx.x; i < tend; i += 256) {
        int d = dst[i];
        int b = d >> NPB_SHIFT;
        int pos = base[b] + atomicAdd(&cnt[b], 1);
        if (pos < CAP)
            bdata[((size_t)g * nbuk + b) * CAP + pos] =
                ((unsigned int)(d & (NPB - 1)) << 16) | (unsigned int)src[i];
    }
}

__global__ __launch_bounds__(1024)
void bucket_scan_kernel(const int* __restrict__ gcount, int* __restrict__ bbase, int nbuk) {
    int g = blockIdx.x;
    __shared__ int sm[1024];
    int v = (threadIdx.x < nbuk) ? gcount[g * nbuk + threadIdx.x] : 0;
    sm[threadIdx.x] = v;
    __syncthreads();
    #pragma unroll
    for (int off = 1; off < 1024; off <<= 1) {
        int t = (threadIdx.x >= off) ? sm[threadIdx.x - off] : 0;
        __syncthreads();
        sm[threadIdx.x] += t;
        __syncthreads();
    }
    if (threadIdx.x < nbuk) bbase[g * nbuk + threadIdx.x] = sm[threadIdx.x] - v;
}

__global__ __launch_bounds__(256)
void build_kernel(const unsigned int* __restrict__ bdata, const int* __restrict__ gcount,
                  const int* __restrict__ bbase, int* __restrict__ arr,
                  unsigned short* __restrict__ col, int n, int nbuk, int e) {
    int g = blockIdx.y;
    int b = blockIdx.x;
    int M = gcount[g * nbuk + b];
    if (M > CAP) M = CAP;
    int base = bbase[g * nbuk + b];
    const unsigned int* rec = bdata + ((size_t)g * nbuk + b) * CAP;
    __shared__ int deg[NPB];
    __shared__ int cursor[NPB];
    if (threadIdx.x < NPB) deg[threadIdx.x] = 0;
    __syncthreads();
    for (int i = threadIdx.x; i < M; i += 256)
        atomicAdd(&deg[rec[i] >> 16], 1);
    __syncthreads();
    if (threadIdx.x < NPB) {
        int d = deg[threadIdx.x];
        int incl = d;
        #pragma unroll
        for (int off = 1; off < NPB; off <<= 1) {
            int t = __shfl_up(incl, off, 64);
            if ((int)threadIdx.x >= off) incl += t;
        }
        cursor[threadIdx.x] = base + incl - d;
        int node = b * NPB + threadIdx.x;
        if (node < n) arr[(size_t)g * n + node] = base + incl;   // end offset
    }
    __syncthreads();
    for (int i = threadIdx.x; i < M; i += 256) {
        unsigned int r = rec[i];
        int p = atomicAdd(&cursor[r >> 16], 1);
        if (p < e) col[(size_t)g * e + p] = (unsigned short)(r & 0xFFFF);
    }
}

// ---------------- conversion: fts [t][node][128] f32 -> xI [node][t][128] bf16 ----------------

__global__ __launch_bounds__(256)
void conv_kernel(const float* __restrict__ fts, unsigned short* __restrict__ xI,
                 int n, int total16) {
    int tid = blockIdx.x * 256 + threadIdx.x;
    if (tid >= total16) return;                 // total16 = T*N*16
    int k = tid & 15;
    int nt = tid >> 4;                          // t*n + node
    int t = nt / n;
    int node = nt - t * n;
    const float* s = fts + (size_t)nt * FD + k * 8;
    float4 a = *(const float4*)s;
    float4 b = *(const float4*)(s + 4);
    uint4 o;
    o.x = pack2(a.x, a.y); o.y = pack2(a.z, a.w);
    o.z = pack2(b.x, b.y); o.w = pack2(b.z, b.w);
    *(uint4*)(xI + (size_t)node * FD4 + t * FD + k * 8) = o;
}

__global__ void pack_weights_kernel(const float* __restrict__ Wl, const float* __restrict__ Wr,
                                    unsigned short* __restrict__ out) {
    int i = blockIdx.x * blockDim.x + threadIdx.x;   // 128*256
    if (i < 128 * 256) {
        int j = i >> 8, k = i & 255;
        float v = (k < 128) ? Wl[j * 128 + k] : Wr[j * 128 + (k - 128)];
        out[i] = f2bf(v);
    }
}

// ---------------- layer-1 gather-mean, batched over graphs: blockIdx.y = t ----------------

__global__ __launch_bounds__(256)
void agg1_kernel(const int* __restrict__ arr_all, const unsigned short* __restrict__ col_all,
                 const unsigned short* __restrict__ xI, unsigned short* __restrict__ mean1I,
                 int n, int e) {
    int g = blockIdx.y;
    int node = (blockIdx.x * 256 + threadIdx.x) >> 4;
    int l = threadIdx.x & 15;
    if (node >= n) return;
    const int* arr = arr_all + (size_t)g * n;
    const unsigned short* col = col_all + (size_t)g * e;
    int beg = (node == 0) ? 0 : arr[node - 1];
    int end = arr[node];
    float acc[8] = {0.f, 0.f, 0.f, 0.f, 0.f, 0.f, 0.f, 0.f};
    const unsigned short* xb = xI + g * FD + l * 8;
    int ed = beg;
    for (; ed + 8 <= end; ed += 8) {
        uint4 v[8];
        #pragma unroll
        for (int j = 0; j < 8; ++j)
            v[j] = *(const uint4*)(xb + (size_t)col[ed + j] * FD4);
        #pragma unroll
        for (int j = 0; j < 8; ++j) add8(acc, v[j]);
    }
    for (; ed < end; ++ed)
        add8(acc, *(const uint4*)(xb + (size_t)col[ed] * FD4));
    int deg = end - beg;
    float inv = 1.f / (float)(deg > 1 ? deg : 1);
    uint4 o;
    o.x = pack2(acc[0] * inv, acc[1] * inv);
    o.y = pack2(acc[2] * inv, acc[3] * inv);
    o.z = pack2(acc[4] * inv, acc[5] * inv);
    o.w = pack2(acc[6] * inv, acc[7] * inv);
    *(uint4*)(mean1I + (size_t)node * FD4 + g * FD + l * 8) = o;
}

// ---------------- layer-2 gather-mean: 1 wave/node, contiguous 1 KB per edge ----------------

__global__ __launch_bounds__(256)
void agg2_kernel(const int* __restrict__ arr, const unsigned short* __restrict__ col,
                 const unsigned short* __restrict__ ysI, unsigned short* __restrict__ mean2I,
                 int n) {
    int node = (blockIdx.x * 256 + threadIdx.x) >> 6;
    int lane = threadIdx.x & 63;
    if (node >= n) return;
    int beg = (node == 0) ? 0 : arr[node - 1];
    int end = arr[node];
    float acc[8] = {0.f, 0.f, 0.f, 0.f, 0.f, 0.f, 0.f, 0.f};
    const unsigned short* xb = ysI + lane * 8;
    int e = beg;
    for (; e + 8 <= end; e += 8) {
        uint4 v[8];
        #pragma unroll
        for (int j = 0; j < 8; ++j)
            v[j] = *(const uint4*)(xb + (size_t)col[e + j] * FD4);
        #pragma unroll
        for (int j = 0; j < 8; ++j) add8(acc, v[j]);
    }
    for (; e < end; ++e)
        add8(acc, *(const uint4*)(xb + (size_t)col[e] * FD4));
    int deg = end - beg;
    float inv = 1.f / (float)(deg > 1 ? deg : 1);
    uint4 o;
    o.x = pack2(acc[0] * inv, acc[1] * inv);
    o.y = pack2(acc[2] * inv, acc[3] * inv);
    o.z = pack2(acc[4] * inv, acc[5] * inv);
    o.w = pack2(acc[6] * inv, acc[7] * inv);
    *(uint4*)(mean2I + (size_t)node * FD4 + lane * 8) = o;
}

// ---------------- SAGE GEMM: LDS-staged Wcat, 64 rows/wave, 256 rows/block ----------------
// out = leaky_relu([Am|Ax] @ Wcat^T + bias). out may alias Am (each wave reads only its
// own 64 rows before writing them). No __restrict__ on Am/out.

__global__ __launch_bounds__(256, 2)
void sage_gemm_kernel(const unsigned short* Am, const unsigned short* __restrict__ Ax,
                      const unsigned short* __restrict__ Wcat, const float* __restrict__ bias,
                      unsigned short* out, int mrows) {
    __shared__ unsigned short Wlds[128 * WROW];
    for (int i = threadIdx.x; i < 128 * 32; i += 256) {
        int row = i >> 5, seg = i & 31;
        *(uint4*)(&Wlds[row * WROW + seg * 8]) = *(const uint4*)(Wcat + row * 256 + seg * 8);
    }
    __syncthreads();

    int wave = threadIdx.x >> 6;
    int lane = threadIdx.x & 63;
    int m = lane & 15, q = lane >> 4;
    int rowBase = blockIdx.x * 256 + wave * 64;

    int arow[4];
    #pragma unroll
    for (int g = 0; g < 4; ++g) {
        int r = rowBase + g * 16 + m;
        arow[g] = (r < mrows) ? r : (mrows - 1);
    }

    f32x4 acc[4][8];
    #pragma unroll
    for (int g = 0; g < 4; ++g)
        #pragma unroll
        for (int ct = 0; ct < 8; ++ct) acc[g][ct] = (f32x4){0.f, 0.f, 0.f, 0.f};

    #pragma unroll
    for (int step = 0; step < 8; ++step) {
        const unsigned short* Asrc = (step < 4) ? Am : Ax;
        int ka = (step & 3) * 32 + q * 8;
        int kw = step * 32 + q * 8;
        bf16x8 bfrag[8];
        #pragma unroll
        for (int ct = 0; ct < 8; ++ct)
            bfrag[ct] = *(const bf16x8*)(&Wlds[(ct * 16 + m) * WROW + kw]);
        #pragma unroll
        for (int g = 0; g < 4; ++g) {
            bf16x8 afrag = *(const bf16x8*)(Asrc + (size_t)arow[g] * FD + ka);
            #pragma unroll
            for (int ct = 0; ct < 8; ++ct)
                acc[g][ct] = __builtin_amdgcn_mfma_f32_16x16x32_bf16(afrag, bfrag[ct], acc[g][ct], 0, 0, 0);
        }
    }

    #pragma unroll
    for (int g = 0; g < 4; ++g) {
        #pragma unroll
        for (int ct = 0; ct < 8; ++ct) {
            int colc = ct * 16 + m;
            float b = bias[colc];
            #pragma unroll
            for (int r = 0; r < 4; ++r) {
                int row = rowBase + g * 16 + q * 4 + r;
                if (row < mrows) {
                    float v = acc[g][ct][r] + b;
                    v = (v >= 0.f) ? v : 0.2f * v;
                    out[(size_t)row * FD + colc] = f2bf(v);
                }
            }
        }
    }
}

// ---------------- layer-2 GEMM fused with classifier (same structure) ----------------

__global__ __launch_bounds__(256, 2)
void gemm2_cls_kernel(const unsigned short* __restrict__ Am, const unsigned short* __restrict__ Ax,
                      const unsigned short* __restrict__ Wcat, const float* __restrict__ bias,
                      const float* __restrict__ Wc, const float* __restrict__ bc,
                      float* __restrict__ logits, int mrows, int nnode) {
    __shared__ unsigned short Wlds[128 * WROW];
    for (int i = threadIdx.x; i < 128 * 32; i += 256) {
        int row = i >> 5, seg = i & 31;
        *(uint4*)(&Wlds[row * WROW + seg * 8]) = *(const uint4*)(Wcat + row * 256 + seg * 8);
    }
    __syncthreads();

    int wave = threadIdx.x >> 6;
    int lane = threadIdx.x & 63;
    int m = lane & 15, q = lane >> 4;
    int rowBase = blockIdx.x * 256 + wave * 64;

    int arow[4];
    #pragma unroll
    for (int g = 0; g < 4; ++g) {
        int r = rowBase + g * 16 + m;
        arow[g] = (r < mrows) ? r : (mrows - 1);
    }

    f32x4 acc[4][8];
    #pragma unroll
    for (int g = 0; g < 4; ++g)
        #pragma unroll
        for (int ct = 0; ct < 8; ++ct) acc[g][ct] = (f32x4){0.f, 0.f, 0.f, 0.f};

    #pragma unroll
    for (int step = 0; step < 8; ++step) {
        const unsigned short* Asrc = (step < 4) ? Am : Ax;
        int ka = (step & 3) * 32 + q * 8;
        int kw = step * 32 + q * 8;
        bf16x8 bfrag[8];
        #pragma unroll
        for (int ct = 0; ct < 8; ++ct)
            bfrag[ct] = *(const bf16x8*)(&Wlds[(ct * 16 + m) * WROW + kw]);
        #pragma unroll
        for (int g = 0; g < 4; ++g) {
            bf16x8 afrag = *(const bf16x8*)(Asrc + (size_t)arow[g] * FD + ka);
            #pragma unroll
            for (int ct = 0; ct < 8; ++ct)
                acc[g][ct] = __builtin_amdgcn_mfma_f32_16x16x32_bf16(afrag, bfrag[ct], acc[g][ct], 0, 0, 0);
        }
    }

    float wc0[8], wc1[8], bb[8];
    #pragma unroll
    for (int ct = 0; ct < 8; ++ct) {
        wc0[ct] = Wc[ct * 16 + m];
        wc1[ct] = Wc[FD + ct * 16 + m];
        bb[ct]  = bias[ct * 16 + m];
    }
    float bc0 = bc[0], bc1 = bc[1];

    #pragma unroll
    for (int g = 0; g < 4; ++g) {
        #pragma unroll
        for (int r = 0; r < 4; ++r) {
            float p0 = 0.f, p1 = 0.f;
            #pragma unroll
            for (int ct = 0; ct < 8; ++ct) {
                float v = acc[g][ct][r] + bb[ct];
                v = (v >= 0.f) ? v : 0.2f * v;
                p0 += v * wc0[ct];
                p1 += v * wc1[ct];
            }
            #pragma unroll
            for (int off = 8; off > 0; off >>= 1) {
                p0 += __shfl_down(p0, off);
                p1 += __shfl_down(p1, off);
            }
            if (m == 0) {
                int row = rowBase + g * 16 + q * 4 + r;
                if (row < mrows) {
                    int node = row >> 2, t = row & 3;
                    size_t base = ((size_t)t * nnode + node) * CC;
                    logits[base]     = p0 + bc0;
                    logits[base + 1] = p1 + bc1;
                }
            }
        }
    }
}

// ---------------- log_softmax over node axis (2-stage online) ----------------

__global__ __launch_bounds__(256)
void lse_partial_kernel(const float* __restrict__ logits, float* __restrict__ pm,
                        float* __restrict__ ps, int n) {
    int tc = blockIdx.y;
    int t = tc >> 1, c = tc & 1;
    const float* p = logits + (size_t)t * n * CC + c;
    float m = -1e30f, s = 0.f;
    for (int i = blockIdx.x * 256 + threadIdx.x; i < n; i += LSE_CH * 256) {
        float v = p[(size_t)i * CC];
        if (v > m) { s = s * __expf(m - v) + 1.f; m = v; }
        else s += __expf(v - m);
    }
    __shared__ float smm[256], sms[256];
    smm[threadIdx.x] = m; sms[threadIdx.x] = s;
    __syncthreads();
    for (int off = 128; off > 0; off >>= 1) {
        if (threadIdx.x < off) {
            float m2 = smm[threadIdx.x + off], s2 = sms[threadIdx.x + off];
            float M = fmaxf(smm[threadIdx.x], m2);
            sms[threadIdx.x] = sms[threadIdx.x] * __expf(smm[threadIdx.x] - M) + s2 * __expf(m2 - M);
            smm[threadIdx.x] = M;
        }
        __syncthreads();
    }
    if (threadIdx.x == 0) { pm[tc * LSE_CH + blockIdx.x] = smm[0]; ps[tc * LSE_CH + blockIdx.x] = sms[0]; }
}

__global__ void lse_final_kernel(const float* __restrict__ pm, const float* __restrict__ ps,
                                 float* __restrict__ lse) {
    int tc = blockIdx.x;
    int lane = threadIdx.x;
    float m = (lane < LSE_CH) ? pm[tc * LSE_CH + lane] : -1e30f;
    float s = (lane < LSE_CH) ? ps[tc * LSE_CH + lane] : 0.f;
    #pragma unroll
    for (int off = 32; off > 0; off >>= 1) {
        float m2 = __shfl_down(m, off);
        float s2 = __shfl_down(s, off);
        float M = fmaxf(m, m2);
        s = s * __expf(m - M) + s2 * __expf(m2 - M);
        m = M;
    }
    if (lane == 0) lse[tc] = m + logf(s);
}

__global__ void sub_lse_kernel(const float* __restrict__ logits, const float* __restrict__ lse,
                               float* __restrict__ out, int total, int n) {
    int i = blockIdx.x * blockDim.x + threadIdx.x;
    if (i < total) {
        int c = i & 1;
        int t = i / (n * CC);
        out[i] = logits[i] - lse[t * CC + c];
    }
}

// ---------------- launch ----------------

extern "C" void kernel_launch(void* const* d_in, const int* in_sizes, int n_in,
                              void* d_out, int out_size, void* d_ws, size_t ws_size,
                              hipStream_t stream) {
    const int* graph = (const int*)d_in[0];
    const float* fts = (const float*)d_in[1];
    const float* W1l = (const float*)d_in[3];
    const float* b1  = (const float*)d_in[4];
    const float* W1r = (const float*)d_in[5];
    const float* W2l = (const float*)d_in[6];
    const float* b2  = (const float*)d_in[7];
    const float* W2r = (const float*)d_in[8];
    const float* Wc  = (const float*)d_in[9];
    const float* bc  = (const float*)d_in[10];
    float* out = (float*)d_out;

    const int T = TT;
    const int E = in_sizes[0] / (T * 2);
    const int N = in_sizes[1] / (T * FD);
    const int NBUK = (N + NPB - 1) >> NPB_SHIFT;

    size_t off = 0;
    auto alloc = [&](size_t bytes) -> char* {
        char* p = (char*)d_ws + off;
        off += (bytes + 511) & ~(size_t)511;
        return p;
    };
    int* arr_all = (int*)alloc((size_t)T * N * 4);
    unsigned short* col_all = (unsigned short*)alloc((size_t)T * E * 2);
    int* gcount = (int*)alloc((size_t)T * NBUK * 4);
    int* bbase  = (int*)alloc((size_t)T * NBUK * 4);
    unsigned short* wcat1 = (unsigned short*)alloc(128 * 256 * 2);
    unsigned short* wcat2 = (unsigned short*)alloc(128 * 256 * 2);
    float* logits = (float*)alloc((size_t)T * N * CC * 4);
    float* pm  = (float*)alloc((size_t)T * CC * LSE_CH * 4);
    float* ps  = (float*)alloc((size_t)T * CC * LSE_CH * 4);
    float* lse = (float*)alloc(T * CC * 4);
    // R1: bdata (CSR build) -> xI (conv..gemm1) -> mean2I (agg2..gemm2).  51.2 MB
    // R2: mean1I (agg1) -> ysI in-place (gemm1..gemm2).                   51.2 MB
    unsigned short* R1 = (unsigned short*)alloc((size_t)N * FD4 * 2);
    unsigned short* R2 = (unsigned short*)alloc((size_t)N * FD4 * 2);
    unsigned int* bdata = (unsigned int*)R1;
    unsigned short* xI = R1;
    unsigned short* mean2I = R1;
    unsigned short* mean1I = R2;
    unsigned short* ysI = R2;

    pack_weights_kernel<<<(128 * 256 + 255) / 256, 256, 0, stream>>>(W1l, W1r, wcat1);
    pack_weights_kernel<<<(128 * 256 + 255) / 256, 256, 0, stream>>>(W2l, W2r, wcat2);

    // CSR build (uses R1 as bdata — must precede conv)
    hipMemsetAsync(gcount, 0, (size_t)T * NBUK * 4, stream);
    dim3 bingrid((E + BIN_TILE - 1) / BIN_TILE, T);
    bin_kernel<<<bingrid, 256, 0, stream>>>(graph, gcount, bdata, E, NBUK);
    bucket_scan_kernel<<<T, 1024, 0, stream>>>(gcount, bbase, NBUK);
    dim3 buildgrid(NBUK, T);
    build_kernel<<<buildgrid, 256, 0, stream>>>(bdata, gcount, bbase, arr_all, col_all, N, NBUK, E);

    // conversion (overwrites R1 with xI)
    int total16 = T * N * 16;
    conv_kernel<<<(total16 + 255) / 256, 256, 0, stream>>>(fts, xI, N, total16);

    // layer 1: batched aggregation (4 graphs), then one 4N-row GEMM in-place
    dim3 agg1grid((N * 16 + 255) / 256, T);
    agg1_kernel<<<agg1grid, 256, 0, stream>>>(arr_all, col_all, xI, mean1I, N, E);
    int mrows = T * N;
    sage_gemm_kernel<<<(mrows + 255) / 256, 256, 0, stream>>>(mean1I, xI, wcat1, b1, ysI, mrows);

    // layer 2: aggregation with last graph (1 KB contiguous gathers), fused GEMM+classifier
    const int* arrL = arr_all + (size_t)(T - 1) * N;
    const unsigned short* colL = col_all + (size_t)(T - 1) * E;
    agg2_kernel<<<(N * 64 + 255) / 256, 256, 0, stream>>>(arrL, colL, ysI, mean2I, N);
    gemm2_cls_kernel<<<(mrows + 255) / 256, 256, 0, stream>>>(mean2I, ysI, wcat2, b2,
                                                              Wc, bc, logits, mrows, N);

    dim3 lgrid(LSE_CH, T * CC);
    lse_partial_kernel<<<lgrid, 256, 0, stream>>>(logits, pm, ps, N);
    lse_final_kernel<<<T * CC, 64, 0, stream>>>(pm, ps, lse);
    int total = T * N * CC;
    sub_lse_kernel<<<(total + 255) / 256, 256, 0, stream>>>(logits, lse, out, total, N);
}

// Round 7
// 582.391 us; speedup vs baseline: 2.7230x; 1.0015x over previous
//
#include <hip/hip_runtime.h>
#include <hip/hip_bf16.h>

#define TT 4
#define FD 128          // F_IN == H == O == 128
#define FD4 512         // interleaved row: 4 t-slices of 128
#define CC 2
#define LSE_CH 32
#define WROW 264        // padded LDS row stride (elems): 528 B -> 4-bank shift/row

// binning parameters
#define NPB 64
#define NPB_SHIFT 6
#define NBUKMAX 1024
#define CAP 1536
#define BIN_TILE 8192

typedef __attribute__((ext_vector_type(8))) short bf16x8;
typedef __attribute__((ext_vector_type(4))) float f32x4;

__device__ __forceinline__ float bf2f(unsigned int h) {
    union { unsigned int u; float f; } v; v.u = h << 16; return v.f;
}
__device__ __forceinline__ unsigned short f2bf(float f) {
    union { float f; unsigned int u; } v; v.f = f;
    unsigned int u = v.u;
    unsigned int r = u + 0x7FFFu + ((u >> 16) & 1u);   // round-to-nearest-even
    return (unsigned short)(r >> 16);
}
__device__ __forceinline__ unsigned int pack2(float lo, float hi) {
    return ((unsigned int)f2bf(hi) << 16) | (unsigned int)f2bf(lo);
}
__device__ __forceinline__ void add8(float* a, uint4 v) {
    a[0] += bf2f(v.x & 0xFFFF); a[1] += bf2f(v.x >> 16);
    a[2] += bf2f(v.y & 0xFFFF); a[3] += bf2f(v.y >> 16);
    a[4] += bf2f(v.z & 0xFFFF); a[5] += bf2f(v.z >> 16);
    a[6] += bf2f(v.w & 0xFFFF); a[7] += bf2f(v.w >> 16);
}

// ---------------- CSR build via two-level binning ----------------

__global__ __launch_bounds__(256)
void bin_kernel(const int* __restrict__ graph, int* __restrict__ gcount,
                unsigned int* __restrict__ bdata, int e, int nbuk) {
    int g = blockIdx.y;
    const int* src = graph + (size_t)g * 2 * e;
    const int* dst = src + e;
    int tbeg = blockIdx.x * BIN_TILE;
    int tend = tbeg + BIN_TILE < e ? tbeg + BIN_TILE : e;
    __shared__ int cnt[NBUKMAX];
    __shared__ int base[NBUKMAX];
    for (int i = threadIdx.x; i < nbuk; i += 256) cnt[i] = 0;
    __syncthreads();
    for (int i = tbeg + threadIdx.x; i < tend; i += 256)
        atomicAdd(&cnt[dst[i] >> NPB_SHIFT], 1);
    __syncthreads();
    for (int i = threadIdx.x; i < nbuk; i += 256) {
        int c = cnt[i];
        base[i] = (c > 0) ? atomicAdd(&gcount[g * nbuk + i], c) : 0;
        cnt[i] = 0;                         // reuse as cursor
    }
    __syncthreads();
    for (int i = tbeg + threadIdx.x; i < tend; i += 256) {
        int d = dst[i];
        int b = d >> NPB_SHIFT;
        int pos = base[b] + atomicAdd(&cnt[b], 1);
        if (pos < CAP)
            bdata[((size_t)g * nbuk + b) * CAP + pos] =
                ((unsigned int)(d & (NPB - 1)) << 16) | (unsigned int)src[i];
    }
}

__global__ __launch_bounds__(1024)
void bucket_scan_kernel(const int* __restrict__ gcount, int* __restrict__ bbase, int nbuk) {
    int g = blockIdx.x;
    __shared__ int sm[1024];
    int v = (threadIdx.x < nbuk) ? gcount[g * nbuk + threadIdx.x] : 0;
    sm[threadIdx.x] = v;
    __syncthreads();
    #pragma unroll
    for (int off = 1; off < 1024; off <<= 1) {
        int t = (threadIdx.x >= off) ? sm[threadIdx.x - off] : 0;
        __syncthreads();
        sm[threadIdx.x] += t;
        __syncthreads();
    }
    if (threadIdx.x < nbuk) bbase[g * nbuk + threadIdx.x] = sm[threadIdx.x] - v;
}

__global__ __launch_bounds__(256)
void build_kernel(const unsigned int* __restrict__ bdata, const int* __restrict__ gcount,
                  const int* __restrict__ bbase, int* __restrict__ arr,
                  unsigned short* __restrict__ col, int n, int nbuk, int e) {
    int g = blockIdx.y;
    int b = blockIdx.x;
    int M = gcount[g * nbuk + b];
    if (M > CAP) M = CAP;
    int base = bbase[g * nbuk + b];
    const unsigned int* rec = bdata + ((size_t)g * nbuk + b) * CAP;
    __shared__ int deg[NPB];
    __shared__ int cursor[NPB];
    if (threadIdx.x < NPB) deg[threadIdx.x] = 0;
    __syncthreads();
    for (int i = threadIdx.x; i < M; i += 256)
        atomicAdd(&deg[rec[i] >> 16], 1);
    __syncthreads();
    if (threadIdx.x < NPB) {
        int d = deg[threadIdx.x];
        int incl = d;
        #pragma unroll
        for (int off = 1; off < NPB; off <<= 1) {
            int t = __shfl_up(incl, off, 64);
            if ((int)threadIdx.x >= off) incl += t;
        }
        cursor[threadIdx.x] = base + incl - d;
        int node = b * NPB + threadIdx.x;
        if (node < n) arr[(size_t)g * n + node] = base + incl;   // end offset
    }
    __syncthreads();
    for (int i = threadIdx.x; i < M; i += 256) {
        unsigned int r = rec[i];
        int p = atomicAdd(&cursor[r >> 16], 1);
        if (p < e) col[(size_t)g * e + p] = (unsigned short)(r & 0xFFFF);
    }
}

// ---------------- conversion: fts [t][node][128] f32 -> xI [node][t][128] bf16 ----------------

__global__ __launch_bounds__(256)
void conv_kernel(const float* __restrict__ fts, unsigned short* __restrict__ xI,
                 int n, int total16) {
    int tid = blockIdx.x * 256 + threadIdx.x;
    if (tid >= total16) return;                 // total16 = T*N*16
    int k = tid & 15;
    int nt = tid >> 4;                          // t*n + node
    int t = nt / n;
    int node = nt - t * n;
    const float* s = fts + (size_t)nt * FD + k * 8;
    float4 a = *(const float4*)s;
    float4 b = *(const float4*)(s + 4);
    uint4 o;
    o.x = pack2(a.x, a.y); o.y = pack2(a.z, a.w);
    o.z = pack2(b.x, b.y); o.w = pack2(b.z, b.w);
    *(uint4*)(xI + (size_t)node * FD4 + t * FD + k * 8) = o;
}

__global__ void pack_weights_kernel(const float* __restrict__ Wl, const float* __restrict__ Wr,
                                    unsigned short* __restrict__ out) {
    int i = blockIdx.x * blockDim.x + threadIdx.x;   // 128*256
    if (i < 128 * 256) {
        int j = i >> 8, k = i & 255;
        float v = (k < 128) ? Wl[j * 128 + k] : Wr[j * 128 + (k - 128)];
        out[i] = f2bf(v);
    }
}

// ---------------- layer-1 gather-mean, batched over graphs: blockIdx.y = t ----------------

__global__ __launch_bounds__(256)
void agg1_kernel(const int* __restrict__ arr_all, const unsigned short* __restrict__ col_all,
                 const unsigned short* __restrict__ xI, unsigned short* __restrict__ mean1I,
                 int n, int e) {
    int g = blockIdx.y;
    int node = (blockIdx.x * 256 + threadIdx.x) >> 4;
    int l = threadIdx.x & 15;
    if (node >= n) return;
    const int* arr = arr_all + (size_t)g * n;
    const unsigned short* col = col_all + (size_t)g * e;
    int beg = (node == 0) ? 0 : arr[node - 1];
    int end = arr[node];
    float acc[8] = {0.f, 0.f, 0.f, 0.f, 0.f, 0.f, 0.f, 0.f};
    const unsigned short* xb = xI + g * FD + l * 8;
    int ed = beg;
    for (; ed + 8 <= end; ed += 8) {
        uint4 v[8];
        #pragma unroll
        for (int j = 0; j < 8; ++j)
            v[j] = *(const uint4*)(xb + (size_t)col[ed + j] * FD4);
        #pragma unroll
        for (int j = 0; j < 8; ++j) add8(acc, v[j]);
    }
    if (ed + 4 <= end) {
        uint4 v[4];
        #pragma unroll
        for (int j = 0; j < 4; ++j)
            v[j] = *(const uint4*)(xb + (size_t)col[ed + j] * FD4);
        #pragma unroll
        for (int j = 0; j < 4; ++j) add8(acc, v[j]);
        ed += 4;
    }
    for (; ed < end; ++ed)
        add8(acc, *(const uint4*)(xb + (size_t)col[ed] * FD4));
    int deg = end - beg;
    float inv = 1.f / (float)(deg > 1 ? deg : 1);
    uint4 o;
    o.x = pack2(acc[0] * inv, acc[1] * inv);
    o.y = pack2(acc[2] * inv, acc[3] * inv);
    o.z = pack2(acc[4] * inv, acc[5] * inv);
    o.w = pack2(acc[6] * inv, acc[7] * inv);
    *(uint4*)(mean1I + (size_t)node * FD4 + g * FD + l * 8) = o;
}

// ---------------- layer-2 gather-mean: 1 wave/node, contiguous 1 KB per edge ----------------

__global__ __launch_bounds__(256)
void agg2_kernel(const int* __restrict__ arr, const unsigned short* __restrict__ col,
                 const unsigned short* __restrict__ ysI, unsigned short* __restrict__ mean2I,
                 int n) {
    int node = (blockIdx.x * 256 + threadIdx.x) >> 6;
    int lane = threadIdx.x & 63;
    if (node >= n) return;
    int beg = (node == 0) ? 0 : arr[node - 1];
    int end = arr[node];
    float acc[8] = {0.f, 0.f, 0.f, 0.f, 0.f, 0.f, 0.f, 0.f};
    const unsigned short* xb = ysI + lane * 8;
    int e = beg;
    for (; e + 8 <= end; e += 8) {
        uint4 v[8];
        #pragma unroll
        for (int j = 0; j < 8; ++j)
            v[j] = *(const uint4*)(xb + (size_t)col[e + j] * FD4);
        #pragma unroll
        for (int j = 0; j < 8; ++j) add8(acc, v[j]);
    }
    if (e + 4 <= end) {
        uint4 v[4];
        #pragma unroll
        for (int j = 0; j < 4; ++j)
            v[j] = *(const uint4*)(xb + (size_t)col[e + j] * FD4);
        #pragma unroll
        for (int j = 0; j < 4; ++j) add8(acc, v[j]);
        e += 4;
    }
    for (; e < end; ++e)
        add8(acc, *(const uint4*)(xb + (size_t)col[e] * FD4));
    int deg = end - beg;
    float inv = 1.f / (float)(deg > 1 ? deg : 1);
    uint4 o;
    o.x = pack2(acc[0] * inv, acc[1] * inv);
    o.y = pack2(acc[2] * inv, acc[3] * inv);
    o.z = pack2(acc[4] * inv, acc[5] * inv);
    o.w = pack2(acc[6] * inv, acc[7] * inv);
    *(uint4*)(mean2I + (size_t)node * FD4 + lane * 8) = o;
}

// ---------------- SAGE GEMM: LDS W, 64 rows/wave, A-prefetch pipeline ----------------
// out = leaky_relu([Am|Ax] @ Wcat^T + bias). out may alias Am (each wave reads all its
// rows' A-frags before its epilogue stores). No __restrict__ on Am/out.

__global__ __launch_bounds__(256, 2)
void sage_gemm_kernel(const unsigned short* Am, const unsigned short* __restrict__ Ax,
                      const unsigned short* __restrict__ Wcat, const float* __restrict__ bias,
                      unsigned short* out, int mrows) {
    __shared__ unsigned short Wlds[128 * WROW];
    for (int i = threadIdx.x; i < 128 * 32; i += 256) {
        int row = i >> 5, seg = i & 31;
        *(uint4*)(&Wlds[row * WROW + seg * 8]) = *(const uint4*)(Wcat + row * 256 + seg * 8);
    }
    __syncthreads();

    int wave = threadIdx.x >> 6;
    int lane = threadIdx.x & 63;
    int m = lane & 15, q = lane >> 4;
    int rowBase = blockIdx.x * 256 + wave * 64;

    int arow[4];
    #pragma unroll
    for (int g = 0; g < 4; ++g) {
        int r = rowBase + g * 16 + m;
        arow[g] = (r < mrows) ? r : (mrows - 1);
    }

    f32x4 acc[4][8];
    #pragma unroll
    for (int g = 0; g < 4; ++g)
        #pragma unroll
        for (int ct = 0; ct < 8; ++ct) acc[g][ct] = (f32x4){0.f, 0.f, 0.f, 0.f};

    bf16x8 af[4], afn[4];
    #pragma unroll
    for (int g = 0; g < 4; ++g)
        af[g] = *(const bf16x8*)(Am + (size_t)arow[g] * FD + q * 8);

    #pragma unroll
    for (int step = 0; step < 8; ++step) {
        if (step < 7) {
            const unsigned short* An = (step + 1 < 4) ? Am : Ax;
            int kan = ((step + 1) & 3) * 32 + q * 8;
            #pragma unroll
            for (int g = 0; g < 4; ++g)
                afn[g] = *(const bf16x8*)(An + (size_t)arow[g] * FD + kan);
        }
        int kw = step * 32 + q * 8;
        bf16x8 bfrag[8];
        #pragma unroll
        for (int ct = 0; ct < 8; ++ct)
            bfrag[ct] = *(const bf16x8*)(&Wlds[(ct * 16 + m) * WROW + kw]);
        #pragma unroll
        for (int g = 0; g < 4; ++g)
            #pragma unroll
            for (int ct = 0; ct < 8; ++ct)
                acc[g][ct] = __builtin_amdgcn_mfma_f32_16x16x32_bf16(af[g], bfrag[ct], acc[g][ct], 0, 0, 0);
        #pragma unroll
        for (int g = 0; g < 4; ++g) af[g] = afn[g];
    }

    #pragma unroll
    for (int g = 0; g < 4; ++g) {
        #pragma unroll
        for (int ct = 0; ct < 8; ++ct) {
            int colc = ct * 16 + m;
            float b = bias[colc];
            #pragma unroll
            for (int r = 0; r < 4; ++r) {
                int row = rowBase + g * 16 + q * 4 + r;
                if (row < mrows) {
                    float v = acc[g][ct][r] + b;
                    v = (v >= 0.f) ? v : 0.2f * v;
                    out[(size_t)row * FD + colc] = f2bf(v);
                }
            }
        }
    }
}

// ---------------- layer-2 GEMM fused with classifier (same structure) ----------------

__global__ __launch_bounds__(256, 2)
void gemm2_cls_kernel(const unsigned short* __restrict__ Am, const unsigned short* __restrict__ Ax,
                      const unsigned short* __restrict__ Wcat, const float* __restrict__ bias,
                      const float* __restrict__ Wc, const float* __restrict__ bc,
                      float* __restrict__ logits, int mrows, int nnode) {
    __shared__ unsigned short Wlds[128 * WROW];
    for (int i = threadIdx.x; i < 128 * 32; i += 256) {
        int row = i >> 5, seg = i & 31;
        *(uint4*)(&Wlds[row * WROW + seg * 8]) = *(const uint4*)(Wcat + row * 256 + seg * 8);
    }
    __syncthreads();

    int wave = threadIdx.x >> 6;
    int lane = threadIdx.x & 63;
    int m = lane & 15, q = lane >> 4;
    int rowBase = blockIdx.x * 256 + wave * 64;

    int arow[4];
    #pragma unroll
    for (int g = 0; g < 4; ++g) {
        int r = rowBase + g * 16 + m;
        arow[g] = (r < mrows) ? r : (mrows - 1);
    }

    f32x4 acc[4][8];
    #pragma unroll
    for (int g = 0; g < 4; ++g)
        #pragma unroll
        for (int ct = 0; ct < 8; ++ct) acc[g][ct] = (f32x4){0.f, 0.f, 0.f, 0.f};

    bf16x8 af[4], afn[4];
    #pragma unroll
    for (int g = 0; g < 4; ++g)
        af[g] = *(const bf16x8*)(Am + (size_t)arow[g] * FD + q * 8);

    #pragma unroll
    for (int step = 0; step < 8; ++step) {
        if (step < 7) {
            const unsigned short* An = (step + 1 < 4) ? Am : Ax;
            int kan = ((step + 1) & 3) * 32 + q * 8;
            #pragma unroll
            for (int g = 0; g < 4; ++g)
                afn[g] = *(const bf16x8*)(An + (size_t)arow[g] * FD + kan);
        }
        int kw = step * 32 + q * 8;
        bf16x8 bfrag[8];
        #pragma unroll
        for (int ct = 0; ct < 8; ++ct)
            bfrag[ct] = *(const bf16x8*)(&Wlds[(ct * 16 + m) * WROW + kw]);
        #pragma unroll
        for (int g = 0; g < 4; ++g)
            #pragma unroll
            for (int ct = 0; ct < 8; ++ct)
                acc[g][ct] = __builtin_amdgcn_mfma_f32_16x16x32_bf16(af[g], bfrag[ct], acc[g][ct], 0, 0, 0);
        #pragma unroll
        for (int g = 0; g < 4; ++g) af[g] = afn[g];
    }

    float wc0[8], wc1[8], bb[8];
    #pragma unroll
    for (int ct = 0; ct < 8; ++ct) {
        wc0[ct] = Wc[ct * 16 + m];
        wc1[ct] = Wc[FD + ct * 16 + m];
        bb[ct]  = bias[ct * 16 + m];
    }
    float bc0 = bc[0], bc1 = bc[1];

    #pragma unroll
    for (int g = 0; g < 4; ++g) {
        #pragma unroll
        for (int r = 0; r < 4; ++r) {
            float p0 = 0.f, p1 = 0.f;
            #pragma unroll
            for (int ct = 0; ct < 8; ++ct) {
                float v = acc[g][ct][r] + bb[ct];
                v = (v >= 0.f) ? v : 0.2f * v;
                p0 += v * wc0[ct];
                p1 += v * wc1[ct];
            }
            #pragma unroll
            for (int off = 8; off > 0; off >>= 1) {
                p0 += __shfl_down(p0, off);
                p1 += __shfl_down(p1, off);
            }
            if (m == 0) {
                int row = rowBase + g * 16 + q * 4 + r;
                if (row < mrows) {
                    int node = row >> 2, t = row & 3;
                    size_t base = ((size_t)t * nnode + node) * CC;
                    logits[base]     = p0 + bc0;
                    logits[base + 1] = p1 + bc1;
                }
            }
        }
    }
}

// ---------------- log_softmax over node axis (2-stage online) ----------------

__global__ __launch_bounds__(256)
void lse_partial_kernel(const float* __restrict__ logits, float* __restrict__ pm,
                        float* __restrict__ ps, int n) {
    int tc = blockIdx.y;
    int t = tc >> 1, c = tc & 1;
    const float* p = logits + (size_t)t * n * CC + c;
    float m = -1e30f, s = 0.f;
    for (int i = blockIdx.x * 256 + threadIdx.x; i < n; i += LSE_CH * 256) {
        float v = p[(size_t)i * CC];
        if (v > m) { s = s * __expf(m - v) + 1.f; m = v; }
        else s += __expf(v - m);
    }
    __shared__ float smm[256], sms[256];
    smm[threadIdx.x] = m; sms[threadIdx.x] = s;
    __syncthreads();
    for (int off = 128; off > 0; off >>= 1) {
        if (threadIdx.x < off) {
            float m2 = smm[threadIdx.x + off], s2 = sms[threadIdx.x + off];
            float M = fmaxf(smm[threadIdx.x], m2);
            sms[threadIdx.x] = sms[threadIdx.x] * __expf(smm[threadIdx.x] - M) + s2 * __expf(m2 - M);
            smm[threadIdx.x] = M;
        }
        __syncthreads();
    }
    if (threadIdx.x == 0) { pm[tc * LSE_CH + blockIdx.x] = smm[0]; ps[tc * LSE_CH + blockIdx.x] = sms[0]; }
}

__global__ void lse_final_kernel(const float* __restrict__ pm, const float* __restrict__ ps,
                                 float* __restrict__ lse) {
    int tc = blockIdx.x;
    int lane = threadIdx.x;
    float m = (lane < LSE_CH) ? pm[tc * LSE_CH + lane] : -1e30f;
    float s = (lane < LSE_CH) ? ps[tc * LSE_CH + lane] : 0.f;
    #pragma unroll
    for (int off = 32; off > 0; off >>= 1) {
        float m2 = __shfl_down(m, off);
        float s2 = __shfl_down(s, off);
        float M = fmaxf(m, m2);
        s = s * __expf(m - M) + s2 * __expf(m2 - M);
        m = M;
    }
    if (lane == 0) lse[tc] = m + logf(s);
}

__global__ void sub_lse_kernel(const float* __restrict__ logits, const float* __restrict__ lse,
                               float* __restrict__ out, int total, int n) {
    int i = blockIdx.x * blockDim.x + threadIdx.x;
    if (i < total) {
        int c = i & 1;
        int t = i / (n * CC);
        out[i] = logits[i] - lse[t * CC + c];
    }
}

// ---------------- launch ----------------

extern "C" void kernel_launch(void* const* d_in, const int* in_sizes, int n_in,
                              void* d_out, int out_size, void* d_ws, size_t ws_size,
                              hipStream_t stream) {
    const int* graph = (const int*)d_in[0];
    const float* fts = (const float*)d_in[1];
    const float* W1l = (const float*)d_in[3];
    const float* b1  = (const float*)d_in[4];
    const float* W1r = (const float*)d_in[5];
    const float* W2l = (const float*)d_in[6];
    const float* b2  = (const float*)d_in[7];
    const float* W2r = (const float*)d_in[8];
    const float* Wc  = (const float*)d_in[9];
    const float* bc  = (const float*)d_in[10];
    float* out = (float*)d_out;

    const int T = TT;
    const int E = in_sizes[0] / (T * 2);
    const int N = in_sizes[1] / (T * FD);
    const int NBUK = (N + NPB - 1) >> NPB_SHIFT;

    size_t off = 0;
    auto alloc = [&](size_t bytes) -> char* {
        char* p = (char*)d_ws + off;
        off += (bytes + 511) & ~(size_t)511;
        return p;
    };
    int* arr_all = (int*)alloc((size_t)T * N * 4);
    unsigned short* col_all = (unsigned short*)alloc((size_t)T * E * 2);
    int* gcount = (int*)alloc((size_t)T * NBUK * 4);
    int* bbase  = (int*)alloc((size_t)T * NBUK * 4);
    unsigned short* wcat1 = (unsigned short*)alloc(128 * 256 * 2);
    unsigned short* wcat2 = (unsigned short*)alloc(128 * 256 * 2);
    float* logits = (float*)alloc((size_t)T * N * CC * 4);
    float* pm  = (float*)alloc((size_t)T * CC * LSE_CH * 4);
    float* ps  = (float*)alloc((size_t)T * CC * LSE_CH * 4);
    float* lse = (float*)alloc(T * CC * 4);
    // R1: bdata (CSR build) -> xI (conv..gemm1) -> mean2I (agg2..gemm2).  51.2 MB
    // R2: mean1I (agg1) -> ysI in-place (gemm1..gemm2).                   51.2 MB
    unsigned short* R1 = (unsigned short*)alloc((size_t)N * FD4 * 2);
    unsigned short* R2 = (unsigned short*)alloc((size_t)N * FD4 * 2);
    unsigned int* bdata = (unsigned int*)R1;
    unsigned short* xI = R1;
    unsigned short* mean2I = R1;
    unsigned short* mean1I = R2;
    unsigned short* ysI = R2;

    pack_weights_kernel<<<(128 * 256 + 255) / 256, 256, 0, stream>>>(W1l, W1r, wcat1);
    pack_weights_kernel<<<(128 * 256 + 255) / 256, 256, 0, stream>>>(W2l, W2r, wcat2);

    // CSR build (uses R1 as bdata — must precede conv)
    hipMemsetAsync(gcount, 0, (size_t)T * NBUK * 4, stream);
    dim3 bingrid((E + BIN_TILE - 1) / BIN_TILE, T);
    bin_kernel<<<bingrid, 256, 0, stream>>>(graph, gcount, bdata, E, NBUK);
    bucket_scan_kernel<<<T, 1024, 0, stream>>>(gcount, bbase, NBUK);
    dim3 buildgrid(NBUK, T);
    build_kernel<<<buildgrid, 256, 0, stream>>>(bdata, gcount, bbase, arr_all, col_all, N, NBUK, E);

    // conversion (overwrites R1 with xI)
    int total16 = T * N * 16;
    conv_kernel<<<(total16 + 255) / 256, 256, 0, stream>>>(fts, xI, N, total16);

    // layer 1: batched aggregation (4 graphs), then one 4N-row GEMM in-place
    dim3 agg1grid((N * 16 + 255) / 256, T);
    agg1_kernel<<<agg1grid, 256, 0, stream>>>(arr_all, col_all, xI, mean1I, N, E);
    int mrows = T * N;
    sage_gemm_kernel<<<(mrows + 255) / 256, 256, 0, stream>>>(mean1I, xI, wcat1, b1, ysI, mrows);

    // layer 2: aggregation with last graph (1 KB contiguous gathers), fused GEMM+classifier
    const int* arrL = arr_all + (size_t)(T - 1) * N;
    const unsigned short* colL = col_all + (size_t)(T - 1) * E;
    agg2_kernel<<<(N * 64 + 255) / 256, 256, 0, stream>>>(arrL, colL, ysI, mean2I, N);
    gemm2_cls_kernel<<<(mrows + 255) / 256, 256, 0, stream>>>(mean2I, ysI, wcat2, b2,
                                                              Wc, bc, logits, mrows, N);

    dim3 lgrid(LSE_CH, T * CC);
    lse_partial_kernel<<<lgrid, 256, 0, stream>>>(logits, pm, ps, N);
    lse_final_kernel<<<T * CC, 64, 0, stream>>>(pm, ps, lse);
    int total = T * N * CC;
    sub_lse_kernel<<<(total + 255) / 256, 256, 0, stream>>>(logits, lse, out, total, N);
}

// Round 8
// 582.003 us; speedup vs baseline: 2.7248x; 1.0007x over previous
//
#include <hip/hip_runtime.h>
#include <hip/hip_bf16.h>

#define TT 4
#define FD 128          // F_IN == H == O == 128
#define FD4 512         // interleaved row: 4 t-slices of 128
#define CC 2
#define LSE_CH 32
#define WROW 264        // padded LDS row stride (elems): 528 B -> 4-bank shift/row

// binning parameters
#define NPB 64
#define NPB_SHIFT 6
#define NBUKMAX 1024
#define CAP 1536
#define BIN_TILE 8192

typedef __attribute__((ext_vector_type(8))) short bf16x8;
typedef __attribute__((ext_vector_type(4))) float f32x4;

__device__ __forceinline__ float bf2f(unsigned int h) {
    union { unsigned int u; float f; } v; v.u = h << 16; return v.f;
}
__device__ __forceinline__ unsigned short f2bf(float f) {
    union { float f; unsigned int u; } v; v.f = f;
    unsigned int u = v.u;
    unsigned int r = u + 0x7FFFu + ((u >> 16) & 1u);   // round-to-nearest-even
    return (unsigned short)(r >> 16);
}
__device__ __forceinline__ unsigned int pack2(float lo, float hi) {
    return ((unsigned int)f2bf(hi) << 16) | (unsigned int)f2bf(lo);
}
__device__ __forceinline__ void add8(float* a, uint4 v) {
    a[0] += bf2f(v.x & 0xFFFF); a[1] += bf2f(v.x >> 16);
    a[2] += bf2f(v.y & 0xFFFF); a[3] += bf2f(v.y >> 16);
    a[4] += bf2f(v.z & 0xFFFF); a[5] += bf2f(v.z >> 16);
    a[6] += bf2f(v.w & 0xFFFF); a[7] += bf2f(v.w >> 16);
}

// ---------------- CSR build via two-level binning ----------------

__global__ __launch_bounds__(256)
void bin_kernel(const int* __restrict__ graph, int* __restrict__ gcount,
                unsigned int* __restrict__ bdata, int e, int nbuk) {
    int g = blockIdx.y;
    const int* src = graph + (size_t)g * 2 * e;
    const int* dst = src + e;
    int tbeg = blockIdx.x * BIN_TILE;
    int tend = tbeg + BIN_TILE < e ? tbeg + BIN_TILE : e;
    __shared__ int cnt[NBUKMAX];
    __shared__ int base[NBUKMAX];
    for (int i = threadIdx.x; i < nbuk; i += 256) cnt[i] = 0;
    __syncthreads();
    for (int i = tbeg + threadIdx.x; i < tend; i += 256)
        atomicAdd(&cnt[dst[i] >> NPB_SHIFT], 1);
    __syncthreads();
    for (int i = threadIdx.x; i < nbuk; i += 256) {
        int c = cnt[i];
        base[i] = (c > 0) ? atomicAdd(&gcount[g * nbuk + i], c) : 0;
        cnt[i] = 0;                         // reuse as cursor
    }
    __syncthreads();
    for (int i = tbeg + threadIdx.x; i < tend; i += 256) {
        int d = dst[i];
        int b = d >> NPB_SHIFT;
        int pos = base[b] + atomicAdd(&cnt[b], 1);
        if (pos < CAP)
            bdata[((size_t)g * nbuk + b) * CAP + pos] =
                ((unsigned int)(d & (NPB - 1)) << 16) | (unsigned int)src[i];
    }
}

__global__ __launch_bounds__(1024)
void bucket_scan_kernel(const int* __restrict__ gcount, int* __restrict__ bbase, int nbuk) {
    int g = blockIdx.x;
    __shared__ int sm[1024];
    int v = (threadIdx.x < nbuk) ? gcount[g * nbuk + threadIdx.x] : 0;
    sm[threadIdx.x] = v;
    __syncthreads();
    #pragma unroll
    for (int off = 1; off < 1024; off <<= 1) {
        int t = (threadIdx.x >= off) ? sm[threadIdx.x - off] : 0;
        __syncthreads();
        sm[threadIdx.x] += t;
        __syncthreads();
    }
    if (threadIdx.x < nbuk) bbase[g * nbuk + threadIdx.x] = sm[threadIdx.x] - v;
}

__global__ __launch_bounds__(256)
void build_kernel(const unsigned int* __restrict__ bdata, const int* __restrict__ gcount,
                  const int* __restrict__ bbase, int* __restrict__ arr,
                  unsigned short* __restrict__ col, int n, int nbuk, int e) {
    int g = blockIdx.y;
    int b = blockIdx.x;
    int M = gcount[g * nbuk + b];
    if (M > CAP) M = CAP;
    int base = bbase[g * nbuk + b];
    const unsigned int* rec = bdata + ((size_t)g * nbuk + b) * CAP;
    __shared__ int deg[NPB];
    __shared__ int cursor[NPB];
    if (threadIdx.x < NPB) deg[threadIdx.x] = 0;
    __syncthreads();
    for (int i = threadIdx.x; i < M; i += 256)
        atomicAdd(&deg[rec[i] >> 16], 1);
    __syncthreads();
    if (threadIdx.x < NPB) {
        int d = deg[threadIdx.x];
        int incl = d;
        #pragma unroll
        for (int off = 1; off < NPB; off <<= 1) {
            int t = __shfl_up(incl, off, 64);
            if ((int)threadIdx.x >= off) incl += t;
        }
        cursor[threadIdx.x] = base + incl - d;
        int node = b * NPB + threadIdx.x;
        if (node < n) arr[(size_t)g * n + node] = base + incl;   // end offset
    }
    __syncthreads();
    for (int i = threadIdx.x; i < M; i += 256) {
        unsigned int r = rec[i];
        int p = atomicAdd(&cursor[r >> 16], 1);
        if (p < e) col[(size_t)g * e + p] = (unsigned short)(r & 0xFFFF);
    }
}

// ---------------- conversion: fts [t][node][128] f32 -> xI [node][t][128] bf16 ----------------

__global__ __launch_bounds__(256)
void conv_kernel(const float* __restrict__ fts, unsigned short* __restrict__ xI,
                 int n, int total16) {
    int tid = blockIdx.x * 256 + threadIdx.x;
    if (tid >= total16) return;                 // total16 = T*N*16
    int k = tid & 15;
    int nt = tid >> 4;                          // t*n + node
    int t = nt / n;
    int node = nt - t * n;
    const float* s = fts + (size_t)nt * FD + k * 8;
    float4 a = *(const float4*)s;
    float4 b = *(const float4*)(s + 4);
    uint4 o;
    o.x = pack2(a.x, a.y); o.y = pack2(a.z, a.w);
    o.z = pack2(b.x, b.y); o.w = pack2(b.z, b.w);
    *(uint4*)(xI + (size_t)node * FD4 + t * FD + k * 8) = o;
}

// packs both weight sets: blockIdx.y selects (W1l,W1r)->wcat1 or (W2l,W2r)->wcat2
__global__ void pack_weights_kernel(const float* __restrict__ W1l, const float* __restrict__ W1r,
                                    const float* __restrict__ W2l, const float* __restrict__ W2r,
                                    unsigned short* __restrict__ o1, unsigned short* __restrict__ o2) {
    int i = blockIdx.x * blockDim.x + threadIdx.x;   // 128*256
    if (i >= 128 * 256) return;
    const float* Wl = blockIdx.y ? W2l : W1l;
    const float* Wr = blockIdx.y ? W2r : W1r;
    unsigned short* out = blockIdx.y ? o2 : o1;
    int j = i >> 8, k = i & 255;
    float v = (k < 128) ? Wl[j * 128 + k] : Wr[j * 128 + (k - 128)];
    out[i] = f2bf(v);
}

// ---------------- layer-1 gather-mean, batched over graphs: blockIdx.y = t ----------------

__global__ __launch_bounds__(256)
void agg1_kernel(const int* __restrict__ arr_all, const unsigned short* __restrict__ col_all,
                 const unsigned short* __restrict__ xI, unsigned short* __restrict__ mean1I,
                 int n, int e) {
    int g = blockIdx.y;
    int node = (blockIdx.x * 256 + threadIdx.x) >> 4;
    int l = threadIdx.x & 15;
    if (node >= n) return;
    const int* arr = arr_all + (size_t)g * n;
    const unsigned short* col = col_all + (size_t)g * e;
    int beg = (node == 0) ? 0 : arr[node - 1];
    int end = arr[node];
    float acc[8] = {0.f, 0.f, 0.f, 0.f, 0.f, 0.f, 0.f, 0.f};
    const unsigned short* xb = xI + g * FD + l * 8;
    int ed = beg;
    for (; ed + 8 <= end; ed += 8) {
        uint4 v[8];
        #pragma unroll
        for (int j = 0; j < 8; ++j)
            v[j] = *(const uint4*)(xb + (size_t)col[ed + j] * FD4);
        #pragma unroll
        for (int j = 0; j < 8; ++j) add8(acc, v[j]);
    }
    if (ed + 4 <= end) {
        uint4 v[4];
        #pragma unroll
        for (int j = 0; j < 4; ++j)
            v[j] = *(const uint4*)(xb + (size_t)col[ed + j] * FD4);
        #pragma unroll
        for (int j = 0; j < 4; ++j) add8(acc, v[j]);
        ed += 4;
    }
    for (; ed < end; ++ed)
        add8(acc, *(const uint4*)(xb + (size_t)col[ed] * FD4));
    int deg = end - beg;
    float inv = 1.f / (float)(deg > 1 ? deg : 1);
    uint4 o;
    o.x = pack2(acc[0] * inv, acc[1] * inv);
    o.y = pack2(acc[2] * inv, acc[3] * inv);
    o.z = pack2(acc[4] * inv, acc[5] * inv);
    o.w = pack2(acc[6] * inv, acc[7] * inv);
    *(uint4*)(mean1I + (size_t)node * FD4 + g * FD + l * 8) = o;
}

// ---------------- layer-2 gather-mean: 1 wave/node, contiguous 1 KB per edge ----------------

__global__ __launch_bounds__(256)
void agg2_kernel(const int* __restrict__ arr, const unsigned short* __restrict__ col,
                 const unsigned short* __restrict__ ysI, unsigned short* __restrict__ mean2I,
                 int n) {
    int node = (blockIdx.x * 256 + threadIdx.x) >> 6;
    int lane = threadIdx.x & 63;
    if (node >= n) return;
    int beg = (node == 0) ? 0 : arr[node - 1];
    int end = arr[node];
    float acc[8] = {0.f, 0.f, 0.f, 0.f, 0.f, 0.f, 0.f, 0.f};
    const unsigned short* xb = ysI + lane * 8;
    int e = beg;
    for (; e + 8 <= end; e += 8) {
        uint4 v[8];
        #pragma unroll
        for (int j = 0; j < 8; ++j)
            v[j] = *(const uint4*)(xb + (size_t)col[e + j] * FD4);
        #pragma unroll
        for (int j = 0; j < 8; ++j) add8(acc, v[j]);
    }
    if (e + 4 <= end) {
        uint4 v[4];
        #pragma unroll
        for (int j = 0; j < 4; ++j)
            v[j] = *(const uint4*)(xb + (size_t)col[e + j] * FD4);
        #pragma unroll
        for (int j = 0; j < 4; ++j) add8(acc, v[j]);
        e += 4;
    }
    for (; e < end; ++e)
        add8(acc, *(const uint4*)(xb + (size_t)col[e] * FD4));
    int deg = end - beg;
    float inv = 1.f / (float)(deg > 1 ? deg : 1);
    uint4 o;
    o.x = pack2(acc[0] * inv, acc[1] * inv);
    o.y = pack2(acc[2] * inv, acc[3] * inv);
    o.z = pack2(acc[4] * inv, acc[5] * inv);
    o.w = pack2(acc[6] * inv, acc[7] * inv);
    *(uint4*)(mean2I + (size_t)node * FD4 + lane * 8) = o;
}

// ---------------- SAGE GEMM: LDS W, 64 rows/wave, depth-2 A-prefetch ----------------
// out = leaky_relu([Am|Ax] @ Wcat^T + bias). out may alias Am (each wave reads all its
// rows' A-frags before its epilogue stores). No __restrict__ on Am/out.

__global__ __launch_bounds__(256, 2)
void sage_gemm_kernel(const unsigned short* Am, const unsigned short* __restrict__ Ax,
                      const unsigned short* __restrict__ Wcat, const float* __restrict__ bias,
                      unsigned short* out, int mrows) {
    int wave = threadIdx.x >> 6;
    int lane = threadIdx.x & 63;
    int m = lane & 15, q = lane >> 4;
    int rowBase = blockIdx.x * 256 + wave * 64;

    int arow[4];
    #pragma unroll
    for (int g = 0; g < 4; ++g) {
        int r = rowBase + g * 16 + m;
        arow[g] = (r < mrows) ? r : (mrows - 1);
    }

    // issue first two A-steps BEFORE LDS fill so cold latency overlaps staging
    bf16x8 af[3][4];
    #pragma unroll
    for (int g = 0; g < 4; ++g)
        af[0][g] = *(const bf16x8*)(Am + (size_t)arow[g] * FD + 0 * 32 + q * 8);
    #pragma unroll
    for (int g = 0; g < 4; ++g)
        af[1][g] = *(const bf16x8*)(Am + (size_t)arow[g] * FD + 1 * 32 + q * 8);

    __shared__ unsigned short Wlds[128 * WROW];
    for (int i = threadIdx.x; i < 128 * 32; i += 256) {
        int row = i >> 5, seg = i & 31;
        *(uint4*)(&Wlds[row * WROW + seg * 8]) = *(const uint4*)(Wcat + row * 256 + seg * 8);
    }
    __syncthreads();

    f32x4 acc[4][8];
    #pragma unroll
    for (int g = 0; g < 4; ++g)
        #pragma unroll
        for (int ct = 0; ct < 8; ++ct) acc[g][ct] = (f32x4){0.f, 0.f, 0.f, 0.f};

    #pragma unroll
    for (int step = 0; step < 8; ++step) {
        if (step < 6) {
            const unsigned short* An = (step + 2 < 4) ? Am : Ax;
            int kan = ((step + 2) & 3) * 32 + q * 8;
            #pragma unroll
            for (int g = 0; g < 4; ++g)
                af[(step + 2) % 3][g] = *(const bf16x8*)(An + (size_t)arow[g] * FD + kan);
        }
        int kw = step * 32 + q * 8;
        bf16x8 bfrag[8];
        #pragma unroll
        for (int ct = 0; ct < 8; ++ct)
            bfrag[ct] = *(const bf16x8*)(&Wlds[(ct * 16 + m) * WROW + kw]);
        #pragma unroll
        for (int g = 0; g < 4; ++g)
            #pragma unroll
            for (int ct = 0; ct < 8; ++ct)
                acc[g][ct] = __builtin_amdgcn_mfma_f32_16x16x32_bf16(af[step % 3][g], bfrag[ct], acc[g][ct], 0, 0, 0);
    }

    #pragma unroll
    for (int g = 0; g < 4; ++g) {
        #pragma unroll
        for (int ct = 0; ct < 8; ++ct) {
            int colc = ct * 16 + m;
            float b = bias[colc];
            #pragma unroll
            for (int r = 0; r < 4; ++r) {
                int row = rowBase + g * 16 + q * 4 + r;
                if (row < mrows) {
                    float v = acc[g][ct][r] + b;
                    v = (v >= 0.f) ? v : 0.2f * v;
                    out[(size_t)row * FD + colc] = f2bf(v);
                }
            }
        }
    }
}

// ---------------- layer-2 GEMM fused with classifier (same structure) ----------------

__global__ __launch_bounds__(256, 2)
void gemm2_cls_kernel(const unsigned short* __restrict__ Am, const unsigned short* __restrict__ Ax,
                      const unsigned short* __restrict__ Wcat, const float* __restrict__ bias,
                      const float* __restrict__ Wc, const float* __restrict__ bc,
                      float* __restrict__ logits, int mrows, int nnode) {
    int wave = threadIdx.x >> 6;
    int lane = threadIdx.x & 63;
    int m = lane & 15, q = lane >> 4;
    int rowBase = blockIdx.x * 256 + wave * 64;

    int arow[4];
    #pragma unroll
    for (int g = 0; g < 4; ++g) {
        int r = rowBase + g * 16 + m;
        arow[g] = (r < mrows) ? r : (mrows - 1);
    }

    bf16x8 af[3][4];
    #pragma unroll
    for (int g = 0; g < 4; ++g)
        af[0][g] = *(const bf16x8*)(Am + (size_t)arow[g] * FD + 0 * 32 + q * 8);
    #pragma unroll
    for (int g = 0; g < 4; ++g)
        af[1][g] = *(const bf16x8*)(Am + (size_t)arow[g] * FD + 1 * 32 + q * 8);

    __shared__ unsigned short Wlds[128 * WROW];
    for (int i = threadIdx.x; i < 128 * 32; i += 256) {
        int row = i >> 5, seg = i & 31;
        *(uint4*)(&Wlds[row * WROW + seg * 8]) = *(const uint4*)(Wcat + row * 256 + seg * 8);
    }
    __syncthreads();

    f32x4 acc[4][8];
    #pragma unroll
    for (int g = 0; g < 4; ++g)
        #pragma unroll
        for (int ct = 0; ct < 8; ++ct) acc[g][ct] = (f32x4){0.f, 0.f, 0.f, 0.f};

    #pragma unroll
    for (int step = 0; step < 8; ++step) {
        if (step < 6) {
            const unsigned short* An = (step + 2 < 4) ? Am : Ax;
            int kan = ((step + 2) & 3) * 32 + q * 8;
            #pragma unroll
            for (int g = 0; g < 4; ++g)
                af[(step + 2) % 3][g] = *(const bf16x8*)(An + (size_t)arow[g] * FD + kan);
        }
        int kw = step * 32 + q * 8;
        bf16x8 bfrag[8];
        #pragma unroll
        for (int ct = 0; ct < 8; ++ct)
            bfrag[ct] = *(const bf16x8*)(&Wlds[(ct * 16 + m) * WROW + kw]);
        #pragma unroll
        for (int g = 0; g < 4; ++g)
            #pragma unroll
            for (int ct = 0; ct < 8; ++ct)
                acc[g][ct] = __builtin_amdgcn_mfma_f32_16x16x32_bf16(af[step % 3][g], bfrag[ct], acc[g][ct], 0, 0, 0);
    }

    float wc0[8], wc1[8], bb[8];
    #pragma unroll
    for (int ct = 0; ct < 8; ++ct) {
        wc0[ct] = Wc[ct * 16 + m];
        wc1[ct] = Wc[FD + ct * 16 + m];
        bb[ct]  = bias[ct * 16 + m];
    }
    float bc0 = bc[0], bc1 = bc[1];

    #pragma unroll
    for (int g = 0; g < 4; ++g) {
        #pragma unroll
        for (int r = 0; r < 4; ++r) {
            float p0 = 0.f, p1 = 0.f;
            #pragma unroll
            for (int ct = 0; ct < 8; ++ct) {
                float v = acc[g][ct][r] + bb[ct];
                v = (v >= 0.f) ? v : 0.2f * v;
                p0 += v * wc0[ct];
                p1 += v * wc1[ct];
            }
            #pragma unroll
            for (int off = 8; off > 0; off >>= 1) {
                p0 += __shfl_down(p0, off);
                p1 += __shfl_down(p1, off);
            }
            if (m == 0) {
                int row = rowBase + g * 16 + q * 4 + r;
                if (row < mrows) {
                    int node = row >> 2, t = row & 3;
                    size_t base = ((size_t)t * nnode + node) * CC;
                    logits[base]     = p0 + bc0;
                    logits[base + 1] = p1 + bc1;
                }
            }
        }
    }
}

// ---------------- log_softmax over node axis (2-stage online) ----------------

__global__ __launch_bounds__(256)
void lse_partial_kernel(const float* __restrict__ logits, float* __restrict__ pm,
                        float* __restrict__ ps, int n) {
    int tc = blockIdx.y;
    int t = tc >> 1, c = tc & 1;
    const float* p = logits + (size_t)t * n * CC + c;
    float m = -1e30f, s = 0.f;
    for (int i = blockIdx.x * 256 + threadIdx.x; i < n; i += LSE_CH * 256) {
        float v = p[(size_t)i * CC];
        if (v > m) { s = s * __expf(m - v) + 1.f; m = v; }
        else s += __expf(v - m);
    }
    __shared__ float smm[256], sms[256];
    smm[threadIdx.x] = m; sms[threadIdx.x] = s;
    __syncthreads();
    for (int off = 128; off > 0; off >>= 1) {
        if (threadIdx.x < off) {
            float m2 = smm[threadIdx.x + off], s2 = sms[threadIdx.x + off];
            float M = fmaxf(smm[threadIdx.x], m2);
            sms[threadIdx.x] = sms[threadIdx.x] * __expf(smm[threadIdx.x] - M) + s2 * __expf(m2 - M);
            smm[threadIdx.x] = M;
        }
        __syncthreads();
    }
    if (threadIdx.x == 0) { pm[tc * LSE_CH + blockIdx.x] = smm[0]; ps[tc * LSE_CH + blockIdx.x] = sms[0]; }
}

// final LSE reduction fused into the subtraction kernel: each block re-reduces the
// 8 x 32 partials (2 KB reads/block) into LDS, then subtracts.
__global__ __launch_bounds__(256)
void sub_lse_kernel(const float* __restrict__ logits, const float* __restrict__ pm,
                    const float* __restrict__ ps, float* __restrict__ out, int total, int n) {
    __shared__ float slse[8];
    int tc = threadIdx.x >> 5;        // 8 groups of 32 lanes
    int l32 = threadIdx.x & 31;
    float m = pm[tc * LSE_CH + l32];
    float s = ps[tc * LSE_CH + l32];
    #pragma unroll
    for (int off = 16; off > 0; off >>= 1) {
        float m2 = __shfl_down(m, off, 32);
        float s2 = __shfl_down(s, off, 32);
        float M = fmaxf(m, m2);
        s = s * __expf(m - M) + s2 * __expf(m2 - M);
        m = M;
    }
    if (l32 == 0) slse[tc] = m + logf(s);
    __syncthreads();
    int i = blockIdx.x * 256 + threadIdx.x;
    if (i < total) {
        int c = i & 1;
        int t = i / (n * CC);
        out[i] = logits[i] - slse[t * CC + c];
    }
}

// ---------------- launch ----------------

extern "C" void kernel_launch(void* const* d_in, const int* in_sizes, int n_in,
                              void* d_out, int out_size, void* d_ws, size_t ws_size,
                              hipStream_t stream) {
    const int* graph = (const int*)d_in[0];
    const float* fts = (const float*)d_in[1];
    const float* W1l = (const float*)d_in[3];
    const float* b1  = (const float*)d_in[4];
    const float* W1r = (const float*)d_in[5];
    const float* W2l = (const float*)d_in[6];
    const float* b2  = (const float*)d_in[7];
    const float* W2r = (const float*)d_in[8];
    const float* Wc  = (const float*)d_in[9];
    const float* bc  = (const float*)d_in[10];
    float* out = (float*)d_out;

    const int T = TT;
    const int E = in_sizes[0] / (T * 2);
    const int N = in_sizes[1] / (T * FD);
    const int NBUK = (N + NPB - 1) >> NPB_SHIFT;

    size_t off = 0;
    auto alloc = [&](size_t bytes) -> char* {
        char* p = (char*)d_ws + off;
        off += (bytes + 511) & ~(size_t)511;
        return p;
    };
    int* arr_all = (int*)alloc((size_t)T * N * 4);
    unsigned short* col_all = (unsigned short*)alloc((size_t)T * E * 2);
    int* gcount = (int*)alloc((size_t)T * NBUK * 4);
    int* bbase  = (int*)alloc((size_t)T * NBUK * 4);
    unsigned short* wcat1 = (unsigned short*)alloc(128 * 256 * 2);
    unsigned short* wcat2 = (unsigned short*)alloc(128 * 256 * 2);
    float* logits = (float*)alloc((size_t)T * N * CC * 4);
    float* pm  = (float*)alloc((size_t)T * CC * LSE_CH * 4);
    float* ps  = (float*)alloc((size_t)T * CC * LSE_CH * 4);
    // R1: bdata (CSR build) -> xI (conv..gemm1) -> mean2I (agg2..gemm2).  51.2 MB
    // R2: mean1I (agg1) -> ysI in-place (gemm1..gemm2).                   51.2 MB
    unsigned short* R1 = (unsigned short*)alloc((size_t)N * FD4 * 2);
    unsigned short* R2 = (unsigned short*)alloc((size_t)N * FD4 * 2);
    unsigned int* bdata = (unsigned int*)R1;
    unsigned short* xI = R1;
    unsigned short* mean2I = R1;
    unsigned short* mean1I = R2;
    unsigned short* ysI = R2;

    dim3 pwgrid((128 * 256 + 255) / 256, 2);
    pack_weights_kernel<<<pwgrid, 256, 0, stream>>>(W1l, W1r, W2l, W2r, wcat1, wcat2);

    // CSR build (uses R1 as bdata — must precede conv)
    hipMemsetAsync(gcount, 0, (size_t)T * NBUK * 4, stream);
    dim3 bingrid((E + BIN_TILE - 1) / BIN_TILE, T);
    bin_kernel<<<bingrid, 256, 0, stream>>>(graph, gcount, bdata, E, NBUK);
    bucket_scan_kernel<<<T, 1024, 0, stream>>>(gcount, bbase, NBUK);
    dim3 buildgrid(NBUK, T);
    build_kernel<<<buildgrid, 256, 0, stream>>>(bdata, gcount, bbase, arr_all, col_all, N, NBUK, E);

    // conversion (overwrites R1 with xI)
    int total16 = T * N * 16;
    conv_kernel<<<(total16 + 255) / 256, 256, 0, stream>>>(fts, xI, N, total16);

    // layer 1: batched aggregation (4 graphs), then one 4N-row GEMM in-place
    dim3 agg1grid((N * 16 + 255) / 256, T);
    agg1_kernel<<<agg1grid, 256, 0, stream>>>(arr_all, col_all, xI, mean1I, N, E);
    int mrows = T * N;
    sage_gemm_kernel<<<(mrows + 255) / 256, 256, 0, stream>>>(mean1I, xI, wcat1, b1, ysI, mrows);

    // layer 2: aggregation with last graph (1 KB contiguous gathers), fused GEMM+classifier
    const int* arrL = arr_all + (size_t)(T - 1) * N;
    const unsigned short* colL = col_all + (size_t)(T - 1) * E;
    agg2_kernel<<<(N * 64 + 255) / 256, 256, 0, stream>>>(arrL, colL, ysI, mean2I, N);
    gemm2_cls_kernel<<<(mrows + 255) / 256, 256, 0, stream>>>(mean2I, ysI, wcat2, b2,
                                                              Wc, bc, logits, mrows, N);

    dim3 lgrid(LSE_CH, T * CC);
    lse_partial_kernel<<<lgrid, 256, 0, stream>>>(logits, pm, ps, N);
    int total = T * N * CC;
    sub_lse_kernel<<<(total + 255) / 256, 256, 0, stream>>>(logits, pm, ps, out, total, N);
}